// Round 6
// baseline (413.358 us; speedup 1.0000x reference)
//
#include <hip/hip_runtime.h>
#include <hip/hip_bf16.h>
#include <cstdint>
#include <cstddef>

#define S 2048
#define D 4096
#define H 32
#define G 8
#define DH 128
#define HD (H*DH)   // 4096
#define GD (G*DH)   // 1024

typedef __bf16 bf16;
typedef __bf16 bf16x4 __attribute__((ext_vector_type(4)));
typedef __bf16 bf16x8 __attribute__((ext_vector_type(8)));
typedef float f32x4 __attribute__((ext_vector_type(4)));

__device__ __forceinline__ void gload16(const void* g, void* l) {
    __builtin_amdgcn_global_load_lds(
        (const __attribute__((address_space(1))) void*)g,
        (__attribute__((address_space(3))) void*)l, 16, 0, 0);
}

#define FENCE() asm volatile("" ::: "memory")
#define BARRIER() do { FENCE(); __builtin_amdgcn_s_barrier(); FENCE(); } while (0)
#define VMCNT(n)  asm volatile("s_waitcnt vmcnt(" #n ")" ::: "memory")
#define LGKMC(n)  do { asm volatile("s_waitcnt lgkmcnt(" #n ")" ::: "memory"); \
                       __builtin_amdgcn_sched_barrier(0); } while (0)

// ---------------------------------------------------------------- cast x -> bf16
__global__ __launch_bounds__(256) void cast_f32_bf16(const float* __restrict__ in,
                                                     bf16* __restrict__ out, int n4)
{
    int i = blockIdx.x * 256 + threadIdx.x;
    if (i < n4) {
        float4 v = reinterpret_cast<const float4*>(in)[i];
        bf16x4 o = { (bf16)v.x, (bf16)v.y, (bf16)v.z, (bf16)v.w };
        reinterpret_cast<bf16x4*>(out)[i] = o;
    }
}

// ---------------------------------------------------------------- transpose -> bf16
template<bool IN_F32>
__global__ __launch_bounds__(256) void transpose_to_bf16(
    const void* __restrict__ in, bf16* __restrict__ out, int R, int C)
{
    const int r0 = blockIdx.y * 64 + (threadIdx.x & 7) * 8;
    const int c0 = blockIdx.x * 256 + (threadIdx.x >> 3) * 8;
    bf16 m[8][8];
    #pragma unroll
    for (int j = 0; j < 8; ++j) {
        if constexpr (IN_F32) {
            const float* p = (const float*)in + (size_t)(r0 + j) * C + c0;
            float4 a = *reinterpret_cast<const float4*>(p);
            float4 b = *reinterpret_cast<const float4*>(p + 4);
            m[j][0] = (bf16)a.x; m[j][1] = (bf16)a.y; m[j][2] = (bf16)a.z; m[j][3] = (bf16)a.w;
            m[j][4] = (bf16)b.x; m[j][5] = (bf16)b.y; m[j][6] = (bf16)b.z; m[j][7] = (bf16)b.w;
        } else {
            const bf16* p = (const bf16*)in + (size_t)(r0 + j) * C + c0;
            bf16x8 v = *reinterpret_cast<const bf16x8*>(p);
            #pragma unroll
            for (int i = 0; i < 8; ++i) m[j][i] = v[i];
        }
    }
    #pragma unroll
    for (int i = 0; i < 8; ++i) {
        bf16x8 ov;
        #pragma unroll
        for (int j = 0; j < 8; ++j) ov[j] = m[j][i];
        *reinterpret_cast<bf16x8*>(out + (size_t)(c0 + i) * R + r0) = ov;
    }
}

// ---------------------------------------------------------------- RoPE in-place (+scale)
__global__ __launch_bounds__(256) void rope_inplace(bf16* __restrict__ Y,
                                                    const float* __restrict__ cosT,
                                                    const float* __restrict__ sinT,
                                                    int ncols, int total, float scale)
{
    int idx = blockIdx.x * 256 + threadIdx.x;
    if (idx >= total) return;
    int pairs = ncols >> 1;
    int s = idx / pairs;
    int p = idx - s * pairs;
    int head = p >> 6;
    int d = p & 63;
    size_t base = (size_t)s * ncols + head * DH;
    float c  = cosT[s * DH + d];
    float sn = sinT[s * DH + d];
    float a = (float)Y[base + d];
    float b = (float)Y[base + d + 64];
    Y[base + d]      = (bf16)((a * c - b * sn) * scale);
    Y[base + d + 64] = (bf16)((b * c + a * sn) * scale);
}

// ================================================================ QKV GEMM: 256x192, pipelined reads
// Grid 8x32 = 256 blocks = 1/CU. BK=64, dbuf 2x56KB. 8 waves (2Mx4N), per-wave 128x48.
// 4 phases/tile (mh,ks); each phase ds_reads the NEXT phase's frags then waits
// lgkmcnt(N_new) (= only older reads drained) -> current frags proven ready -> 12 MFMA.
// Stages: all 7 units of tile t+1 issued at phA; vmcnt(0)+barrier at phD makes every
// wave's async LDS writes visible before the cross-tile read-ahead.
__global__ __launch_bounds__(512, 2) void gemm192(
    const bf16* __restrict__ A, const bf16* __restrict__ Bt,
    bf16* __restrict__ Qout, bf16* __restrict__ Kout, bf16* __restrict__ Vout, int K)
{
    extern __shared__ char smem[];   // buf d @ d*57344: A 32KB | B @ +32768 (24KB)
    const int tid = threadIdx.x, lane = tid & 63, wave = tid >> 6;
    const int wr = wave >> 2, wc = wave & 3;
    const int l15 = lane & 15, lhi = lane >> 4;
    const int r8 = lane >> 3, c8 = lane & 7;
    const int csw = ((c8 ^ r8) << 3);          // pre-swizzled source chunk (elems)

    const int bid = blockIdx.x;
    const int swz = (bid & 7) * 32 + (bid >> 3);   // XCD x owns M-panel x
    const int bm = (swz >> 5) * 256, bn = (swz & 31) * 192;
    const int NT = K >> 6;

    auto stageAll = [&](int buf, int t) {      // 7 gload16/thread
        #pragma unroll
        for (int u = 0; u < 3; ++u)
            gload16(Bt + (size_t)(bn + u * 64 + wave * 8 + r8) * K + (t << 6) + csw,
                    smem + buf * 57344 + 32768 + u * 8192 + wave * 1024);
        #pragma unroll
        for (int u = 0; u < 4; ++u)
            gload16(A + (size_t)(bm + u * 64 + wave * 8 + r8) * K + (t << 6) + csw,
                    smem + buf * 57344 + u * 8192 + wave * 1024);
    };
    auto rdA = [&](const char* Cb, int mh, int ks, bf16x8* af) {
        #pragma unroll
        for (int m = 0; m < 4; ++m) {
            int row = wr * 128 + mh * 64 + m * 16 + l15;
            int ch = (ks * 4 + lhi) ^ (l15 & 7);
            af[m] = *reinterpret_cast<const bf16x8*>(Cb + row * 128 + ch * 16);
        }
    };
    auto rdB = [&](const char* Cb, int ks, bf16x8* bfv) {
        #pragma unroll
        for (int n = 0; n < 3; ++n) {
            int row = wc * 48 + n * 16 + l15;
            int ch = (ks * 4 + lhi) ^ (l15 & 7);
            bfv[n] = *reinterpret_cast<const bf16x8*>(Cb + 32768 + row * 128 + ch * 16);
        }
    };

    f32x4 acc[8][3] = {};
    auto mmc = [&](int mh, const bf16x8* af, const bf16x8* bfv) {
        __builtin_amdgcn_s_setprio(1);
        #pragma unroll
        for (int m = 0; m < 4; ++m)
            #pragma unroll
            for (int n = 0; n < 3; ++n)
                acc[mh * 4 + m][n] = __builtin_amdgcn_mfma_f32_16x16x32_bf16(
                    af[m], bfv[n], acc[mh * 4 + m][n], 0, 0, 0);
        __builtin_amdgcn_s_setprio(0);
    };

    bf16x8 a_cur[4], a_nxt[4], bk0[3], bk1[3];

    // prologue: tile0 -> buf0; read phA frags
    stageAll(0, 0);
    VMCNT(0);
    BARRIER();
    rdB(smem, 0, bk0);
    rdA(smem, 0, 0, a_cur);     // 7 reads outstanding

    for (int t = 0; t < NT; ++t) {
        const char* cur = smem + (t & 1) * 57344;
        const char* nxb = smem + ((t + 1) & 1) * 57344;
        const int nb = (t + 1) & 1;
        const int tn = (t + 1 < NT) ? t + 1 : t;

        // phA: MFMA (mh0,ks0); read (mh0,ks1); stage tile t+1 (7 loads)
        rdA(cur, 0, 1, a_nxt);
        rdB(cur, 1, bk1);           // 7 new ds_reads
        stageAll(nb, tn);
        LGKMC(7);                   // older reads (a_cur,bk0) drained
        mmc(0, a_cur, bk0);
        BARRIER();

        // phB: MFMA (mh0,ks1); read (mh1,ks0)
        rdA(cur, 1, 0, a_cur);      // 4 new
        LGKMC(4);
        mmc(0, a_nxt, bk1);
        BARRIER();

        // phC: MFMA (mh1,ks0); read (mh1,ks1)
        rdA(cur, 1, 1, a_nxt);      // 4 new
        LGKMC(4);
        mmc(1, a_cur, bk0);
        BARRIER();

        // phD: MFMA (mh1,ks1); cross-tile read-ahead from fresh buffer
        VMCNT(0);                   // this wave's 7 stage loads landed
        BARRIER();                  // ...and every other wave's too
        rdA(nxb, 0, 0, a_cur);
        rdB(nxb, 0, bk0);           // 7 new ds_reads (next tile phA frags)
        LGKMC(7);                   // phC's 4 drained -> a_nxt ready
        mmc(1, a_nxt, bk1);
        BARRIER();
    }

    #pragma unroll
    for (int m = 0; m < 8; ++m) {
        int r0 = bm + wr * 128 + m * 16 + lhi * 4;
        #pragma unroll
        for (int n = 0; n < 3; ++n) {
            int c = bn + wc * 48 + n * 16 + l15;
            #pragma unroll
            for (int j = 0; j < 4; ++j) {
                bf16 v = (bf16)acc[m][n][j];
                if (c < HD)            Qout[(size_t)(r0 + j) * HD + c] = v;
                else if (c < HD + GD)  Kout[(size_t)(r0 + j) * GD + (c - HD)] = v;
                else                   Vout[(size_t)(r0 + j) * GD + (c - HD - GD)] = v;
            }
        }
    }
}

// ================================================================ Wo GEMM: 256x128, 3-buf, pipelined reads
// 256 blocks = 1/CU. BK=64, 3 bufs x 48KB. 8 waves (4Mx2N), per-wave 64x64.
// 2 phases/tile; ph0 stages all 6 units of t+2; ph1's vmcnt(6) leaves exactly those 6
// -> tile t+1 proven landed; barrier; then read-ahead t+1's ks0 frags.
__global__ __launch_bounds__(512, 2) void gemm3b(
    const bf16* __restrict__ A, const bf16* __restrict__ Bt,
    float* __restrict__ C, int N, int K, int nbn)
{
    extern __shared__ char smem[];   // buf b @ b*49152: A 32KB, B @ +32768 (16KB)
    const int tid = threadIdx.x, lane = tid & 63, wave = tid >> 6;
    const int wr = wave >> 1, wc = wave & 1;
    const int l15 = lane & 15, lhi = lane >> 4;
    const int r8 = lane >> 3, c8 = lane & 7;
    const int csw = ((c8 ^ r8) << 3);

    const int nwg = gridDim.x, qq = nwg >> 3;
    const int swz = (blockIdx.x & 7) * qq + (blockIdx.x >> 3);
    const int bm = (swz / nbn) * 256, bn = (swz % nbn) * 128;
    const int NT = K >> 6;

    auto stageAll = [&](int buf, int t) {      // 6 gload16/thread
        #pragma unroll
        for (int u = 0; u < 4; ++u)
            gload16(A + (size_t)(bm + u * 64 + wave * 8 + r8) * K + (t << 6) + csw,
                    smem + buf * 49152 + u * 8192 + wave * 1024);
        #pragma unroll
        for (int u = 0; u < 2; ++u)
            gload16(Bt + (size_t)(bn + u * 64 + wave * 8 + r8) * K + (t << 6) + csw,
                    smem + buf * 49152 + 32768 + u * 8192 + wave * 1024);
    };
    auto rdA = [&](const char* Ab, int ks, bf16x8* af) {
        #pragma unroll
        for (int m = 0; m < 4; ++m) {
            int row = wr * 64 + m * 16 + l15;
            int ch = (ks * 4 + lhi) ^ (l15 & 7);
            af[m] = *reinterpret_cast<const bf16x8*>(Ab + row * 128 + ch * 16);
        }
    };
    auto rdB = [&](const char* Ab, int ks, bf16x8* bfv) {
        #pragma unroll
        for (int n = 0; n < 4; ++n) {
            int row = wc * 64 + n * 16 + l15;
            int ch = (ks * 4 + lhi) ^ (l15 & 7);
            bfv[n] = *reinterpret_cast<const bf16x8*>(Ab + 32768 + row * 128 + ch * 16);
        }
    };

    f32x4 acc[4][4] = {};
    auto mmc = [&](const bf16x8* af, const bf16x8* bfv) {
        __builtin_amdgcn_s_setprio(1);
        #pragma unroll
        for (int m = 0; m < 4; ++m)
            #pragma unroll
            for (int n = 0; n < 4; ++n)
                acc[m][n] = __builtin_amdgcn_mfma_f32_16x16x32_bf16(af[m], bfv[n], acc[m][n], 0, 0, 0);
        __builtin_amdgcn_s_setprio(0);
    };

    bf16x8 a_cur[4], b_cur[4], a_nxt[4], b_nxt[4];

    // prologue: tiles 0,1
    stageAll(0, 0);
    stageAll(1, (1 < NT) ? 1 : 0);
    VMCNT(6);                       // tile0 landed
    BARRIER();
    rdA(smem, 0, a_cur);
    rdB(smem, 0, b_cur);            // 8 reads outstanding

    for (int t = 0; t < NT; ++t) {
        const char* cur = smem + (t % 3) * 49152;
        const char* nxb = smem + ((t + 1) % 3) * 49152;
        const int sb = (t + 2) % 3;
        const int st = (t + 2 < NT) ? t + 2 : NT - 1;

        // ph0: MFMA ks0; read ks1; stage tile t+2
        rdA(cur, 1, a_nxt);
        rdB(cur, 1, b_nxt);         // 8 new
        stageAll(sb, st);
        LGKMC(8);
        mmc(a_cur, b_cur);
        BARRIER();

        // ph1: MFMA ks1; ensure t+1 landed; read-ahead t+1 ks0
        VMCNT(6);                   // leaves only the 6 just-issued -> t+1 landed
        BARRIER();
        rdA(nxb, 0, a_cur);
        rdB(nxb, 0, b_cur);         // 8 new
        LGKMC(8);
        mmc(a_nxt, b_nxt);
        BARRIER();
    }

    #pragma unroll
    for (int m = 0; m < 4; ++m) {
        int r0 = bm + wr * 64 + m * 16 + lhi * 4;
        #pragma unroll
        for (int n = 0; n < 4; ++n) {
            int c = bn + wc * 64 + n * 16 + l15;
            #pragma unroll
            for (int j = 0; j < 4; ++j)
                C[(size_t)(r0 + j) * N + c] = acc[m][n][j];
        }
    }
}

// ---------------------------------------------------------------- fallback GEMM (round-1)
#define BM 128
#define BN 128
#define BK 32
#define LDSK 40

template<bool OUT_BF16>
__global__ __launch_bounds__(256) void gemm_aBf16(
    const bf16* __restrict__ A,
    const float* __restrict__ B0, const float* __restrict__ B1,
    void* __restrict__ C0, void* __restrict__ C1,
    int M, int N, int K)
{
    __shared__ alignas(16) bf16 Al[BM][LDSK];
    __shared__ alignas(16) bf16 Bt[BN][LDSK];

    const float* __restrict__ B = blockIdx.z ? B1 : B0;
    void* __restrict__ C = blockIdx.z ? C1 : C0;

    const int tid  = threadIdx.x;
    const int lane = tid & 63;
    const int wave = tid >> 6;
    const int wm = (wave >> 1) * 64;
    const int wn = (wave & 1) * 64;
    const int bm = blockIdx.y * BM;
    const int bn = blockIdx.x * BN;
    const int l15 = lane & 15;
    const int lhi = lane >> 4;

    f32x4 acc[4][4] = {};

    for (int k0 = 0; k0 < K; k0 += BK) {
        #pragma unroll
        for (int it = 0; it < 2; ++it) {
            int idx = it * 256 + tid;
            int row = idx >> 2;
            int ko  = idx & 3;
            bf16x8 v = *reinterpret_cast<const bf16x8*>(
                A + (size_t)(bm + row) * K + k0 + ko * 8);
            *reinterpret_cast<bf16x8*>(&Al[row][ko * 8]) = v;
        }
        {
            int n = tid & 127;
            int kbase = (tid >> 7) * 8;
            const float* bp = B + (size_t)k0 * N + bn + n;
            #pragma unroll
            for (int half = 0; half < 2; ++half) {
                bf16x8 v;
                #pragma unroll
                for (int j = 0; j < 8; ++j)
                    v[j] = (bf16)bp[(size_t)(half * 16 + kbase + j) * N];
                *reinterpret_cast<bf16x8*>(&Bt[n][half * 16 + kbase]) = v;
            }
        }
        __syncthreads();

        bf16x8 af[4], bfv[4];
        #pragma unroll
        for (int m = 0; m < 4; ++m)
            af[m] = *reinterpret_cast<const bf16x8*>(&Al[wm + m * 16 + l15][lhi * 8]);
        #pragma unroll
        for (int n = 0; n < 4; ++n)
            bfv[n] = *reinterpret_cast<const bf16x8*>(&Bt[wn + n * 16 + l15][lhi * 8]);
        #pragma unroll
        for (int m = 0; m < 4; ++m)
            #pragma unroll
            for (int n = 0; n < 4; ++n)
                acc[m][n] = __builtin_amdgcn_mfma_f32_16x16x32_bf16(
                    af[m], bfv[n], acc[m][n], 0, 0, 0);
        __syncthreads();
    }

    #pragma unroll
    for (int m = 0; m < 4; ++m) {
        int r0 = bm + wm + m * 16 + lhi * 4;
        #pragma unroll
        for (int n = 0; n < 4; ++n) {
            int c = bn + wn + n * 16 + l15;
            #pragma unroll
            for (int j = 0; j < 4; ++j) {
                if constexpr (OUT_BF16)
                    reinterpret_cast<bf16*>(C)[(size_t)(r0 + j) * N + c] = (bf16)acc[m][n][j];
                else
                    reinterpret_cast<float*>(C)[(size_t)(r0 + j) * N + c] = acc[m][n][j];
            }
        }
    }
}

// ---------------------------------------------------------------- flash attention v4
// 8 waves (512 thr), QBLK=128 (16 q-rows/wave), KVBLK=64, dbuf K/V (64KB) + P (16KB)
// = 80KB LDS -> 2 blocks/CU = 16 waves/CU. stage(t+1) before compute(t), one
// vmcnt(0)+barrier per tile. MASK on last two tiles. g == XCD for K/V L2 locality.
#define QBLK 128
#define KVBLK 64
#define NQT (S/QBLK)

template<bool MASK>
__device__ __forceinline__ void attn_tile(
    int t0, int q0, int wave, int l15, int lhi,
    const bf16x8* qf, const char* Kl, const char* Vl, char* Plw,
    f32x4* o, float* m_i, float* l_i)
{
    f32x4 sc[4] = {};
    __builtin_amdgcn_s_setprio(1);
    #pragma unroll
    for (int n = 0; n < 4; ++n) {
        int row = n * 16 + l15;
        #pragma unroll
        for (int kk = 0; kk < 4; ++kk) {
            bf16x8 kf = *reinterpret_cast<const bf16x8*>(
                Kl + row * 256 + ((((kk * 4 + lhi)) ^ (l15 & 7)) << 4));
            sc[n] = __builtin_amdgcn_mfma_f32_16x16x32_bf16(qf[kk], kf, sc[n], 0, 0, 0);
        }
    }
    __builtin_amdgcn_s_setprio(0);

    float corr[4];
    #pragma unroll
    for (int j = 0; j < 4; ++j) {
        const int qr = q0 + wave * 16 + lhi * 4 + j;
        float vals[4];
        float mx = -1e30f;
        #pragma unroll
        for (int n = 0; n < 4; ++n) {
            float v = sc[n][j];
            if constexpr (MASK) {
                int t = t0 + n * 16 + l15;
                if (t > qr) v = -1e30f;
            }
            vals[n] = v;
            mx = fmaxf(mx, v);
        }
        #pragma unroll
        for (int ms = 1; ms < 16; ms <<= 1)
            mx = fmaxf(mx, __shfl_xor(mx, ms, 16));
        float mnew = fmaxf(m_i[j], mx);
        float cr = __expf(m_i[j] - mnew);
        float rsum = 0.f;
        #pragma unroll
        for (int n = 0; n < 4; ++n) {
            float p = __expf(vals[n] - mnew);
            rsum += p;
            int r = lhi * 4 + j;
            int off = ((r << 7) + ((n * 16 + l15) << 1)) ^ ((r & 7) << 4);
            *reinterpret_cast<bf16*>(Plw + off) = (bf16)p;
        }
        #pragma unroll
        for (int ms = 1; ms < 16; ms <<= 1)
            rsum += __shfl_xor(rsum, ms, 16);
        l_i[j] = l_i[j] * cr + rsum;
        m_i[j] = mnew;
        corr[j] = cr;
    }

    #pragma unroll
    for (int n = 0; n < 8; ++n)
        #pragma unroll
        for (int j = 0; j < 4; ++j)
            o[n][j] *= corr[j];

    __builtin_amdgcn_s_setprio(1);
    #pragma unroll
    for (int kk = 0; kk < 2; ++kk) {
        bf16x8 pf = *reinterpret_cast<const bf16x8*>(
            Plw + (l15 << 7) + ((((kk * 4 + lhi)) ^ (l15 & 7)) << 4));
        #pragma unroll
        for (int n = 0; n < 8; ++n) {
            int d = n * 16 + l15;
            bf16x8 vf = *reinterpret_cast<const bf16x8*>(
                Vl + (d << 7) + ((((kk * 4 + lhi)) ^ (d & 7)) << 4));
            o[n] = __builtin_amdgcn_mfma_f32_16x16x32_bf16(pf, vf, o[n], 0, 0, 0);
        }
    }
    __builtin_amdgcn_s_setprio(0);
}

__global__ __launch_bounds__(512, 4) void flash_fwd4(
    const bf16* __restrict__ Q, const bf16* __restrict__ Kr,
    const bf16* __restrict__ VtG, bf16* __restrict__ ctx)
{
    extern __shared__ char fsm[];   // buf b: K @ b*32768, V @ +16384; P @ 65536 (8x2KB)

    const int tid  = threadIdx.x;
    const int lane = tid & 63;
    const int wave = tid >> 6;
    const int l15 = lane & 15;
    const int lhi = lane >> 4;
    const int bid = blockIdx.x;
    const int qt = (NQT - 1) - (bid >> 5);               // longest tiles first
    const int h  = ((bid & 7) << 2) | ((bid >> 3) & 3);  // g == bid%8 == XCD
    const int g  = h >> 2;
    const int q0 = qt * QBLK;
    char* Plw = fsm + 65536 + wave * 2048;

    bf16x8 qf[4];
    {
        const bf16* qp = Q + (size_t)(q0 + wave * 16 + l15) * HD + h * DH + lhi * 8;
        #pragma unroll
        for (int kk = 0; kk < 4; ++kk)
            qf[kk] = *reinterpret_cast<const bf16x8*>(qp + kk * 32);
    }

    f32x4 o[8] = {};
    float m_i[4] = { -1e30f, -1e30f, -1e30f, -1e30f };
    float l_i[4] = {};

    auto stage = [&](int t0, int buf) {
        char* Kl = fsm + buf * 32768;
        char* Vl = Kl + 16384;
        #pragma unroll
        for (int t = 0; t < 2; ++t) {
            int ch = t * 512 + tid;
            {
                int row = ch >> 4, ci = ch & 15;
                gload16(Kr + (size_t)(t0 + row) * GD + g * DH + ((ci ^ (row & 7)) << 3),
                        Kl + ch * 16);
            }
            {
                int d = ch >> 3, ci = ch & 7;
                gload16(VtG + (size_t)(g * DH + d) * S + t0 + ((ci ^ (d & 7)) << 3),
                        Vl + ch * 16);
            }
        }
    };

    const int nt = 2 * qt + 2;
    stage(0, 0);
    VMCNT(0);
    BARRIER();

    for (int it = 0; it < nt; ++it) {
        if (it + 1 < nt) stage((it + 1) * KVBLK, (it + 1) & 1);
        const char* Kl = fsm + (it & 1) * 32768;
        const char* Vl = Kl + 16384;
        if (it >= nt - 2)
            attn_tile<true>(it * KVBLK, q0, wave, l15, lhi, qf, Kl, Vl, Plw, o, m_i, l_i);
        else
            attn_tile<false>(it * KVBLK, q0, wave, l15, lhi, qf, Kl, Vl, Plw, o, m_i, l_i);
        VMCNT(0);
        BARRIER();
    }

    #pragma unroll
    for (int n = 0; n < 8; ++n) {
        int c = h * DH + n * 16 + l15;
        #pragma unroll
        for (int j = 0; j < 4; ++j) {
            int r = q0 + wave * 16 + lhi * 4 + j;
            ctx[(size_t)r * HD + c] = (bf16)(o[n][j] / l_i[j]);
        }
    }
}

// ---------------------------------------------------------------- launch
extern "C" void kernel_launch(void* const* d_in, const int* in_sizes, int n_in,
                              void* d_out, int out_size, void* d_ws, size_t ws_size,
                              hipStream_t stream)
{
    const float* x    = (const float*)d_in[0];
    const float* cosT = (const float*)d_in[2];
    const float* sinT = (const float*)d_in[3];
    const float* Wq   = (const float*)d_in[4];
    const float* Wk   = (const float*)d_in[5];
    const float* Wv   = (const float*)d_in[6];
    const float* Wo   = (const float*)d_in[7];
    float* out = (float*)d_out;

    const size_t MB = (size_t)1 << 20;
    char* ws = (char*)d_ws;
    bf16* xb  = (bf16*)ws;                         // 16MB
    bf16* ctx = (bf16*)(ws + 16 * MB);             // 16MB
    bf16* Qb  = (bf16*)d_out;                      // d_out scratch (dead until final GEMM)
    bf16* Kb  = Qb + (size_t)S * HD;
    bf16* Vb  = Kb + (size_t)S * GD;
    bf16* VtG = Vb + (size_t)S * GD;

    const bool fast = ws_size >= 112 * MB;
    const float qscale = 0.08838834764831845f;

    hipFuncSetAttribute(reinterpret_cast<const void*>(&flash_fwd4),
                        hipFuncAttributeMaxDynamicSharedMemorySize, 81920);

    cast_f32_bf16<<<(S * D / 4 + 255) / 256, 256, 0, stream>>>(x, xb, S * D / 4);

    if (fast) {
        bf16* Wqkvt = (bf16*)(ws + 32 * MB);       // [6144][4096] bf16 = 48MB
        bf16* Wot   = (bf16*)(ws + 80 * MB);       // [4096][4096] bf16 = 32MB

        transpose_to_bf16<true><<<dim3(HD / 256, D / 64), 256, 0, stream>>>(Wq, Wqkvt, D, HD);
        transpose_to_bf16<true><<<dim3(GD / 256, D / 64), 256, 0, stream>>>(Wk, Wqkvt + (size_t)HD * D, D, GD);
        transpose_to_bf16<true><<<dim3(GD / 256, D / 64), 256, 0, stream>>>(Wv, Wqkvt + (size_t)(HD + GD) * D, D, GD);
        transpose_to_bf16<true><<<dim3(D / 256, HD / 64), 256, 0, stream>>>(Wo, Wot, HD, D);

        hipFuncSetAttribute(reinterpret_cast<const void*>(&gemm192),
                            hipFuncAttributeMaxDynamicSharedMemorySize, 114688);
        hipFuncSetAttribute(reinterpret_cast<const void*>(&gemm3b),
                            hipFuncAttributeMaxDynamicSharedMemorySize, 147456);

        // QKV: 256x192 tiles -> 8x32 = 256 blocks = 1/CU
        gemm192<<<256, 512, 114688, stream>>>(xb, Wqkvt, Qb, Kb, Vb, D);

        rope_inplace<<<(S * HD / 2 + 255) / 256, 256, 0, stream>>>(Qb, cosT, sinT, HD, S * HD / 2, qscale);
        rope_inplace<<<(S * GD / 2 + 255) / 256, 256, 0, stream>>>(Kb, cosT, sinT, GD, S * GD / 2, 1.0f);

        transpose_to_bf16<false><<<dim3(GD / 256, S / 64), 256, 0, stream>>>(Vb, VtG, S, GD);

        flash_fwd4<<<NQT * H, 512, 81920, stream>>>(Qb, Kb, VtG, ctx);

        // Wo: 256x128 tiles, 8x32 = 256 blocks
        gemm3b<<<256, 512, 147456, stream>>>(ctx, Wot, out, D, HD, 32);
    } else {
        gemm_aBf16<true><<<dim3(HD / BN, S / BM, 1), 256, 0, stream>>>(
            xb, Wq, Wq, (void*)Qb, (void*)Qb, S, HD, D);
        gemm_aBf16<true><<<dim3(GD / BN, S / BM, 2), 256, 0, stream>>>(
            xb, Wk, Wv, (void*)Kb, (void*)Vb, S, GD, D);

        rope_inplace<<<(S * HD / 2 + 255) / 256, 256, 0, stream>>>(Qb, cosT, sinT, HD, S * HD / 2, qscale);
        rope_inplace<<<(S * GD / 2 + 255) / 256, 256, 0, stream>>>(Kb, cosT, sinT, GD, S * GD / 2, 1.0f);

        transpose_to_bf16<false><<<dim3(GD / 256, S / 64), 256, 0, stream>>>(Vb, VtG, S, GD);

        flash_fwd4<<<NQT * H, 512, 81920, stream>>>(Qb, Kb, VtG, ctx);

        gemm_aBf16<false><<<dim3(D / BN, S / BM, 1), 256, 0, stream>>>(
            ctx, Wo, Wo, (void*)out, (void*)out, S, D, HD);
    }

    (void)in_sizes; (void)n_in; (void)out_size; (void)ws_size;
}

// Round 7
// 366.107 us; speedup vs baseline: 1.1291x; 1.1291x over previous
//
#include <hip/hip_runtime.h>
#include <hip/hip_bf16.h>
#include <cstdint>
#include <cstddef>

#define S 2048
#define D 4096
#define H 32
#define G 8
#define DH 128
#define HD (H*DH)   // 4096
#define GD (G*DH)   // 1024

typedef __bf16 bf16;
typedef __bf16 bf16x4 __attribute__((ext_vector_type(4)));
typedef __bf16 bf16x8 __attribute__((ext_vector_type(8)));
typedef float f32x4 __attribute__((ext_vector_type(4)));

__device__ __forceinline__ void gload16(const void* g, void* l) {
    __builtin_amdgcn_global_load_lds(
        (const __attribute__((address_space(1))) void*)g,
        (__attribute__((address_space(3))) void*)l, 16, 0, 0);
}

#define FENCE() asm volatile("" ::: "memory")
#define BARRIER() do { FENCE(); __builtin_amdgcn_s_barrier(); FENCE(); } while (0)
#define VMCNT(n)  asm volatile("s_waitcnt vmcnt(" #n ")" ::: "memory")
#define LGKM0()   do { asm volatile("s_waitcnt lgkmcnt(0)" ::: "memory"); \
                       __builtin_amdgcn_sched_barrier(0); } while (0)

// ---------------------------------------------------------------- cast x -> bf16
__global__ __launch_bounds__(256) void cast_f32_bf16(const float* __restrict__ in,
                                                     bf16* __restrict__ out, int n4)
{
    int i = blockIdx.x * 256 + threadIdx.x;
    if (i < n4) {
        float4 v = reinterpret_cast<const float4*>(in)[i];
        bf16x4 o = { (bf16)v.x, (bf16)v.y, (bf16)v.z, (bf16)v.w };
        reinterpret_cast<bf16x4*>(out)[i] = o;
    }
}

// ---------------------------------------------------------------- transpose -> bf16
template<bool IN_F32>
__global__ __launch_bounds__(256) void transpose_to_bf16(
    const void* __restrict__ in, bf16* __restrict__ out, int R, int C)
{
    const int r0 = blockIdx.y * 64 + (threadIdx.x & 7) * 8;
    const int c0 = blockIdx.x * 256 + (threadIdx.x >> 3) * 8;
    bf16 m[8][8];
    #pragma unroll
    for (int j = 0; j < 8; ++j) {
        if constexpr (IN_F32) {
            const float* p = (const float*)in + (size_t)(r0 + j) * C + c0;
            float4 a = *reinterpret_cast<const float4*>(p);
            float4 b = *reinterpret_cast<const float4*>(p + 4);
            m[j][0] = (bf16)a.x; m[j][1] = (bf16)a.y; m[j][2] = (bf16)a.z; m[j][3] = (bf16)a.w;
            m[j][4] = (bf16)b.x; m[j][5] = (bf16)b.y; m[j][6] = (bf16)b.z; m[j][7] = (bf16)b.w;
        } else {
            const bf16* p = (const bf16*)in + (size_t)(r0 + j) * C + c0;
            bf16x8 v = *reinterpret_cast<const bf16x8*>(p);
            #pragma unroll
            for (int i = 0; i < 8; ++i) m[j][i] = v[i];
        }
    }
    #pragma unroll
    for (int i = 0; i < 8; ++i) {
        bf16x8 ov;
        #pragma unroll
        for (int j = 0; j < 8; ++j) ov[j] = m[j][i];
        *reinterpret_cast<bf16x8*>(out + (size_t)(c0 + i) * R + r0) = ov;
    }
}

// ---------------------------------------------------------------- RoPE in-place (+scale)
__global__ __launch_bounds__(256) void rope_inplace(bf16* __restrict__ Y,
                                                    const float* __restrict__ cosT,
                                                    const float* __restrict__ sinT,
                                                    int ncols, int total, float scale)
{
    int idx = blockIdx.x * 256 + threadIdx.x;
    if (idx >= total) return;
    int pairs = ncols >> 1;
    int s = idx / pairs;
    int p = idx - s * pairs;
    int head = p >> 6;
    int d = p & 63;
    size_t base = (size_t)s * ncols + head * DH;
    float c  = cosT[s * DH + d];
    float sn = sinT[s * DH + d];
    float a = (float)Y[base + d];
    float b = (float)Y[base + d + 64];
    Y[base + d]      = (bf16)((a * c - b * sn) * scale);
    Y[base + d + 64] = (bf16)((b * c + a * sn) * scale);
}

// ================================================================ QKV GEMM: 256x192, m201 phase pattern
// Grid 8x32 = 256 blocks = 1/CU. BK=64, dbuf 2x56KB. 8 waves (2Mx4N), per-wave 128x48.
// Per phase: {7 ds_reads (this phase's operands); stage 1-2 units of t+1; [counted
// vmcnt]; BARRIER; lgkmcnt(0)+sched_barrier; setprio; 12 MFMA; setprio; BARRIER}.
// ds_read latency hides under barrier #1; MFMA cluster starts operand-complete.
// vmcnt(4)@ph1 drains this tile's A1,A3 (needed ph2); vmcnt(2)@ph3 drains t+1's
// B0,B1,B2,A0,A2 (needed t+1 ph0). Never drains to 0 in the loop.
__global__ __launch_bounds__(512, 2) void gemm192(
    const bf16* __restrict__ A, const bf16* __restrict__ Bt,
    bf16* __restrict__ Qout, bf16* __restrict__ Kout, bf16* __restrict__ Vout, int K)
{
    extern __shared__ char smem[];   // buf d @ d*57344: A 32KB | B @ +32768 (24KB)
    const int tid = threadIdx.x, lane = tid & 63, wave = tid >> 6;
    const int wr = wave >> 2, wc = wave & 3;
    const int l15 = lane & 15, lhi = lane >> 4;
    const int r8 = lane >> 3, c8 = lane & 7;
    const int csw = ((c8 ^ r8) << 3);          // pre-swizzled source chunk (elems)

    const int bid = blockIdx.x;
    const int swz = (bid & 7) * 32 + (bid >> 3);   // XCD x owns M-panel x
    const int bm = (swz >> 5) * 256, bn = (swz & 31) * 192;
    const int NT = K >> 6;

    auto stA = [&](int buf, int u, int t) {    // A unit u: rows u*64..u*64+63
        gload16(A + (size_t)(bm + u * 64 + wave * 8 + r8) * K + (t << 6) + csw,
                smem + buf * 57344 + u * 8192 + wave * 1024);
    };
    auto stB = [&](int buf, int u, int t) {    // B unit u: rows u*64..u*64+63
        gload16(Bt + (size_t)(bn + u * 64 + wave * 8 + r8) * K + (t << 6) + csw,
                smem + buf * 57344 + 32768 + u * 8192 + wave * 1024);
    };
    auto rdA = [&](const char* Cb, int mh, int ks, bf16x8* af) {
        #pragma unroll
        for (int m = 0; m < 4; ++m) {
            int row = wr * 128 + mh * 64 + m * 16 + l15;
            int ch = (ks * 4 + lhi) ^ (l15 & 7);
            af[m] = *reinterpret_cast<const bf16x8*>(Cb + row * 128 + ch * 16);
        }
    };
    auto rdB = [&](const char* Cb, int ks, bf16x8* bfv) {
        #pragma unroll
        for (int n = 0; n < 3; ++n) {
            int row = wc * 48 + n * 16 + l15;
            int ch = (ks * 4 + lhi) ^ (l15 & 7);
            bfv[n] = *reinterpret_cast<const bf16x8*>(Cb + 32768 + row * 128 + ch * 16);
        }
    };

    f32x4 acc[8][3] = {};
    auto mmc = [&](int mh, const bf16x8* af, const bf16x8* bfv) {
        LGKM0();
        __builtin_amdgcn_s_setprio(1);
        #pragma unroll
        for (int m = 0; m < 4; ++m)
            #pragma unroll
            for (int n = 0; n < 3; ++n)
                acc[mh * 4 + m][n] = __builtin_amdgcn_mfma_f32_16x16x32_bf16(
                    af[m], bfv[n], acc[mh * 4 + m][n], 0, 0, 0);
        __builtin_amdgcn_s_setprio(0);
    };

    bf16x8 af[4], bk[3];

    // prologue: tile0 -> buf0 in steady-state issue order
    stB(0, 0, 0); stB(0, 1, 0); stB(0, 2, 0);
    stA(0, 0, 0); stA(0, 2, 0); stA(0, 1, 0); stA(0, 3, 0);
    VMCNT(0);
    BARRIER();

    for (int t = 0; t < NT; ++t) {
        const char* cur = smem + (t & 1) * 57344;
        const int nb = (t + 1) & 1;
        const int tn = (t + 1 < NT) ? t + 1 : t;   // tail: dummy restage, dead buffer

        // ph0: (mh0, ks0)
        rdA(cur, 0, 0, af); rdB(cur, 0, bk);
        stB(nb, 0, tn); stB(nb, 1, tn);
        BARRIER();
        mmc(0, af, bk);
        BARRIER();

        // ph1: (mh0, ks1)
        rdA(cur, 0, 1, af); rdB(cur, 1, bk);
        stB(nb, 2, tn); stA(nb, 0, tn);
        VMCNT(4);                 // drains this tile's A1,A3 (needed ph2)
        BARRIER();
        mmc(0, af, bk);
        BARRIER();

        // ph2: (mh1, ks0)
        rdA(cur, 1, 0, af); rdB(cur, 0, bk);
        stA(nb, 2, tn); stA(nb, 1, tn);
        BARRIER();
        mmc(1, af, bk);
        BARRIER();

        // ph3: (mh1, ks1)
        rdA(cur, 1, 1, af); rdB(cur, 1, bk);
        stA(nb, 3, tn);
        VMCNT(2);                 // drains t+1's B0,B1,B2,A0,A2 (needed t+1 ph0)
        BARRIER();
        mmc(1, af, bk);
        BARRIER();
    }

    #pragma unroll
    for (int m = 0; m < 8; ++m) {
        int r0 = bm + wr * 128 + m * 16 + lhi * 4;
        #pragma unroll
        for (int n = 0; n < 3; ++n) {
            int c = bn + wc * 48 + n * 16 + l15;
            #pragma unroll
            for (int j = 0; j < 4; ++j) {
                bf16 v = (bf16)acc[m][n][j];
                if (c < HD)            Qout[(size_t)(r0 + j) * HD + c] = v;
                else if (c < HD + GD)  Kout[(size_t)(r0 + j) * GD + (c - HD)] = v;
                else                   Vout[(size_t)(r0 + j) * GD + (c - HD - GD)] = v;
            }
        }
    }
}

// ================================================================ Wo GEMM: 256x128, 3-buf, m201 phase pattern
// 256 blocks = 1/CU. BK=64, 3 bufs x 48KB. 8 waves (4Mx2N), per-wave 64x64.
// 2 phases/tile; stages 3+3 units of t+2; vmcnt(6)@ph1 (FIFO: leaves exactly the 6
// just-issued -> tile t+1 fully landed before its reads).
__global__ __launch_bounds__(512, 2) void gemm3b(
    const bf16* __restrict__ A, const bf16* __restrict__ Bt,
    float* __restrict__ C, int N, int K, int nbn)
{
    extern __shared__ char smem[];   // buf b @ b*49152: A 32KB, B @ +32768 (16KB)
    const int tid = threadIdx.x, lane = tid & 63, wave = tid >> 6;
    const int wr = wave >> 1, wc = wave & 1;
    const int l15 = lane & 15, lhi = lane >> 4;
    const int r8 = lane >> 3, c8 = lane & 7;
    const int csw = ((c8 ^ r8) << 3);

    const int nwg = gridDim.x, qq = nwg >> 3;
    const int swz = (blockIdx.x & 7) * qq + (blockIdx.x >> 3);
    const int bm = (swz / nbn) * 256, bn = (swz % nbn) * 128;
    const int NT = K >> 6;

    auto stA = [&](int buf, int u, int t) {
        gload16(A + (size_t)(bm + u * 64 + wave * 8 + r8) * K + (t << 6) + csw,
                smem + buf * 49152 + u * 8192 + wave * 1024);
    };
    auto stB = [&](int buf, int u, int t) {
        gload16(Bt + (size_t)(bn + u * 64 + wave * 8 + r8) * K + (t << 6) + csw,
                smem + buf * 49152 + 32768 + u * 8192 + wave * 1024);
    };
    auto rdA = [&](const char* Ab, int ks, bf16x8* af) {
        #pragma unroll
        for (int m = 0; m < 4; ++m) {
            int row = wr * 64 + m * 16 + l15;
            int ch = (ks * 4 + lhi) ^ (l15 & 7);
            af[m] = *reinterpret_cast<const bf16x8*>(Ab + row * 128 + ch * 16);
        }
    };
    auto rdB = [&](const char* Ab, int ks, bf16x8* bfv) {
        #pragma unroll
        for (int n = 0; n < 4; ++n) {
            int row = wc * 64 + n * 16 + l15;
            int ch = (ks * 4 + lhi) ^ (l15 & 7);
            bfv[n] = *reinterpret_cast<const bf16x8*>(Ab + 32768 + row * 128 + ch * 16);
        }
    };

    f32x4 acc[4][4] = {};
    auto mmc = [&](const bf16x8* af, const bf16x8* bfv) {
        LGKM0();
        __builtin_amdgcn_s_setprio(1);
        #pragma unroll
        for (int m = 0; m < 4; ++m)
            #pragma unroll
            for (int n = 0; n < 4; ++n)
                acc[m][n] = __builtin_amdgcn_mfma_f32_16x16x32_bf16(af[m], bfv[n], acc[m][n], 0, 0, 0);
        __builtin_amdgcn_s_setprio(0);
    };

    bf16x8 af[4], bv[4];

    // prologue: tiles 0,1 staged; tile0 guaranteed
    #pragma unroll
    for (int u = 0; u < 4; ++u) stA(0, u, 0);
    stB(0, 0, 0); stB(0, 1, 0);
    #pragma unroll
    for (int u = 0; u < 4; ++u) stA(1, u, (1 < NT) ? 1 : 0);
    stB(1, 0, (1 < NT) ? 1 : 0); stB(1, 1, (1 < NT) ? 1 : 0);
    VMCNT(6);
    BARRIER();

    for (int t = 0; t < NT; ++t) {
        const char* cur = smem + (t % 3) * 49152;
        const int sb = (t + 2) % 3;
        const int st = (t + 2 < NT) ? t + 2 : NT - 1;

        // ph0: ks0
        rdA(cur, 0, af); rdB(cur, 0, bv);
        stA(sb, 0, st); stA(sb, 1, st); stA(sb, 2, st);
        BARRIER();
        mmc(af, bv);
        BARRIER();

        // ph1: ks1
        rdA(cur, 1, af); rdB(cur, 1, bv);
        stA(sb, 3, st); stB(sb, 0, st); stB(sb, 1, st);
        VMCNT(6);                 // leaves only the 6 just-issued -> t+1 landed
        BARRIER();
        mmc(af, bv);
        BARRIER();
    }

    #pragma unroll
    for (int m = 0; m < 4; ++m) {
        int r0 = bm + wr * 64 + m * 16 + lhi * 4;
        #pragma unroll
        for (int n = 0; n < 4; ++n) {
            int c = bn + wc * 64 + n * 16 + l15;
            #pragma unroll
            for (int j = 0; j < 4; ++j)
                C[(size_t)(r0 + j) * N + c] = acc[m][n][j];
        }
    }
}

// ---------------------------------------------------------------- fallback GEMM (round-1)
#define BM 128
#define BN 128
#define BK 32
#define LDSK 40

template<bool OUT_BF16>
__global__ __launch_bounds__(256) void gemm_aBf16(
    const bf16* __restrict__ A,
    const float* __restrict__ B0, const float* __restrict__ B1,
    void* __restrict__ C0, void* __restrict__ C1,
    int M, int N, int K)
{
    __shared__ alignas(16) bf16 Al[BM][LDSK];
    __shared__ alignas(16) bf16 Bt[BN][LDSK];

    const float* __restrict__ B = blockIdx.z ? B1 : B0;
    void* __restrict__ C = blockIdx.z ? C1 : C0;

    const int tid  = threadIdx.x;
    const int lane = tid & 63;
    const int wave = tid >> 6;
    const int wm = (wave >> 1) * 64;
    const int wn = (wave & 1) * 64;
    const int bm = blockIdx.y * BM;
    const int bn = blockIdx.x * BN;
    const int l15 = lane & 15;
    const int lhi = lane >> 4;

    f32x4 acc[4][4] = {};

    for (int k0 = 0; k0 < K; k0 += BK) {
        #pragma unroll
        for (int it = 0; it < 2; ++it) {
            int idx = it * 256 + tid;
            int row = idx >> 2;
            int ko  = idx & 3;
            bf16x8 v = *reinterpret_cast<const bf16x8*>(
                A + (size_t)(bm + row) * K + k0 + ko * 8);
            *reinterpret_cast<bf16x8*>(&Al[row][ko * 8]) = v;
        }
        {
            int n = tid & 127;
            int kbase = (tid >> 7) * 8;
            const float* bp = B + (size_t)k0 * N + bn + n;
            #pragma unroll
            for (int half = 0; half < 2; ++half) {
                bf16x8 v;
                #pragma unroll
                for (int j = 0; j < 8; ++j)
                    v[j] = (bf16)bp[(size_t)(half * 16 + kbase + j) * N];
                *reinterpret_cast<bf16x8*>(&Bt[n][half * 16 + kbase]) = v;
            }
        }
        __syncthreads();

        bf16x8 af[4], bfv[4];
        #pragma unroll
        for (int m = 0; m < 4; ++m)
            af[m] = *reinterpret_cast<const bf16x8*>(&Al[wm + m * 16 + l15][lhi * 8]);
        #pragma unroll
        for (int n = 0; n < 4; ++n)
            bfv[n] = *reinterpret_cast<const bf16x8*>(&Bt[wn + n * 16 + l15][lhi * 8]);
        #pragma unroll
        for (int m = 0; m < 4; ++m)
            #pragma unroll
            for (int n = 0; n < 4; ++n)
                acc[m][n] = __builtin_amdgcn_mfma_f32_16x16x32_bf16(
                    af[m], bfv[n], acc[m][n], 0, 0, 0);
        __syncthreads();
    }

    #pragma unroll
    for (int m = 0; m < 4; ++m) {
        int r0 = bm + wm + m * 16 + lhi * 4;
        #pragma unroll
        for (int n = 0; n < 4; ++n) {
            int c = bn + wn + n * 16 + l15;
            #pragma unroll
            for (int j = 0; j < 4; ++j) {
                if constexpr (OUT_BF16)
                    reinterpret_cast<bf16*>(C)[(size_t)(r0 + j) * N + c] = (bf16)acc[m][n][j];
                else
                    reinterpret_cast<float*>(C)[(size_t)(r0 + j) * N + c] = acc[m][n][j];
            }
        }
    }
}

// ---------------------------------------------------------------- flash attention v4b
// 8 waves (512 thr), QBLK=128 (16 q-rows/wave), KVBLK=64, dbuf K/V (64KB) + P (16KB)
// = 80KB LDS -> 2 blocks/CU. NO launch-bounds min-wave constraint (r6's (512,4)
// forced VGPR=64 -> spills, FETCH 2.4x). MASK on last two tiles. g == XCD.
#define QBLK 128
#define KVBLK 64
#define NQT (S/QBLK)

template<bool MASK>
__device__ __forceinline__ void attn_tile(
    int t0, int q0, int wave, int l15, int lhi,
    const bf16x8* qf, const char* Kl, const char* Vl, char* Plw,
    f32x4* o, float* m_i, float* l_i)
{
    f32x4 sc[4] = {};
    __builtin_amdgcn_s_setprio(1);
    #pragma unroll
    for (int n = 0; n < 4; ++n) {
        int row = n * 16 + l15;
        #pragma unroll
        for (int kk = 0; kk < 4; ++kk) {
            bf16x8 kf = *reinterpret_cast<const bf16x8*>(
                Kl + row * 256 + ((((kk * 4 + lhi)) ^ (l15 & 7)) << 4));
            sc[n] = __builtin_amdgcn_mfma_f32_16x16x32_bf16(qf[kk], kf, sc[n], 0, 0, 0);
        }
    }
    __builtin_amdgcn_s_setprio(0);

    float corr[4];
    #pragma unroll
    for (int j = 0; j < 4; ++j) {
        const int qr = q0 + wave * 16 + lhi * 4 + j;
        float vals[4];
        float mx = -1e30f;
        #pragma unroll
        for (int n = 0; n < 4; ++n) {
            float v = sc[n][j];
            if constexpr (MASK) {
                int t = t0 + n * 16 + l15;
                if (t > qr) v = -1e30f;
            }
            vals[n] = v;
            mx = fmaxf(mx, v);
        }
        #pragma unroll
        for (int ms = 1; ms < 16; ms <<= 1)
            mx = fmaxf(mx, __shfl_xor(mx, ms, 16));
        float mnew = fmaxf(m_i[j], mx);
        float cr = __expf(m_i[j] - mnew);
        float rsum = 0.f;
        #pragma unroll
        for (int n = 0; n < 4; ++n) {
            float p = __expf(vals[n] - mnew);
            rsum += p;
            int r = lhi * 4 + j;
            int off = ((r << 7) + ((n * 16 + l15) << 1)) ^ ((r & 7) << 4);
            *reinterpret_cast<bf16*>(Plw + off) = (bf16)p;
        }
        #pragma unroll
        for (int ms = 1; ms < 16; ms <<= 1)
            rsum += __shfl_xor(rsum, ms, 16);
        l_i[j] = l_i[j] * cr + rsum;
        m_i[j] = mnew;
        corr[j] = cr;
    }

    #pragma unroll
    for (int n = 0; n < 8; ++n)
        #pragma unroll
        for (int j = 0; j < 4; ++j)
            o[n][j] *= corr[j];

    __builtin_amdgcn_s_setprio(1);
    #pragma unroll
    for (int kk = 0; kk < 2; ++kk) {
        bf16x8 pf = *reinterpret_cast<const bf16x8*>(
            Plw + (l15 << 7) + ((((kk * 4 + lhi)) ^ (l15 & 7)) << 4));
        #pragma unroll
        for (int n = 0; n < 8; ++n) {
            int d = n * 16 + l15;
            bf16x8 vf = *reinterpret_cast<const bf16x8*>(
                Vl + (d << 7) + ((((kk * 4 + lhi)) ^ (d & 7)) << 4));
            o[n] = __builtin_amdgcn_mfma_f32_16x16x32_bf16(pf, vf, o[n], 0, 0, 0);
        }
    }
    __builtin_amdgcn_s_setprio(0);
}

__global__ __launch_bounds__(512) void flash_fwd4(
    const bf16* __restrict__ Q, const bf16* __restrict__ Kr,
    const bf16* __restrict__ VtG, bf16* __restrict__ ctx)
{
    extern __shared__ char fsm[];   // buf b: K @ b*32768, V @ +16384; P @ 65536 (8x2KB)

    const int tid  = threadIdx.x;
    const int lane = tid & 63;
    const int wave = tid >> 6;
    const int l15 = lane & 15;
    const int lhi = lane >> 4;
    const int bid = blockIdx.x;
    const int qt = (NQT - 1) - (bid >> 5);               // longest tiles first
    const int h  = ((bid & 7) << 2) | ((bid >> 3) & 3);  // g == bid%8 == XCD
    const int g  = h >> 2;
    const int q0 = qt * QBLK;
    char* Plw = fsm + 65536 + wave * 2048;

    bf16x8 qf[4];
    {
        const bf16* qp = Q + (size_t)(q0 + wave * 16 + l15) * HD + h * DH + lhi * 8;
        #pragma unroll
        for (int kk = 0; kk < 4; ++kk)
            qf[kk] = *reinterpret_cast<const bf16x8*>(qp + kk * 32);
    }

    f32x4 o[8] = {};
    float m_i[4] = { -1e30f, -1e30f, -1e30f, -1e30f };
    float l_i[4] = {};

    auto stage = [&](int t0, int buf) {
        char* Kl = fsm + buf * 32768;
        char* Vl = Kl + 16384;
        #pragma unroll
        for (int t = 0; t < 2; ++t) {
            int ch = t * 512 + tid;
            {
                int row = ch >> 4, ci = ch & 15;
                gload16(Kr + (size_t)(t0 + row) * GD + g * DH + ((ci ^ (row & 7)) << 3),
                        Kl + ch * 16);
            }
            {
                int d = ch >> 3, ci = ch & 7;
                gload16(VtG + (size_t)(g * DH + d) * S + t0 + ((ci ^ (d & 7)) << 3),
                        Vl + ch * 16);
            }
        }
    };

    const int nt = 2 * qt + 2;
    stage(0, 0);
    VMCNT(0);
    BARRIER();

    for (int it = 0; it < nt; ++it) {
        if (it + 1 < nt) stage((it + 1) * KVBLK, (it + 1) & 1);
        const char* Kl = fsm + (it & 1) * 32768;
        const char* Vl = Kl + 16384;
        if (it >= nt - 2)
            attn_tile<true>(it * KVBLK, q0, wave, l15, lhi, qf, Kl, Vl, Plw, o, m_i, l_i);
        else
            attn_tile<false>(it * KVBLK, q0, wave, l15, lhi, qf, Kl, Vl, Plw, o, m_i, l_i);
        VMCNT(0);
        BARRIER();
    }

    #pragma unroll
    for (int n = 0; n < 8; ++n) {
        int c = h * DH + n * 16 + l15;
        #pragma unroll
        for (int j = 0; j < 4; ++j) {
            int r = q0 + wave * 16 + lhi * 4 + j;
            ctx[(size_t)r * HD + c] = (bf16)(o[n][j] / l_i[j]);
        }
    }
}

// ---------------------------------------------------------------- launch
extern "C" void kernel_launch(void* const* d_in, const int* in_sizes, int n_in,
                              void* d_out, int out_size, void* d_ws, size_t ws_size,
                              hipStream_t stream)
{
    const float* x    = (const float*)d_in[0];
    const float* cosT = (const float*)d_in[2];
    const float* sinT = (const float*)d_in[3];
    const float* Wq   = (const float*)d_in[4];
    const float* Wk   = (const float*)d_in[5];
    const float* Wv   = (const float*)d_in[6];
    const float* Wo   = (const float*)d_in[7];
    float* out = (float*)d_out;

    const size_t MB = (size_t)1 << 20;
    char* ws = (char*)d_ws;
    bf16* xb  = (bf16*)ws;                         // 16MB
    bf16* ctx = (bf16*)(ws + 16 * MB);             // 16MB
    bf16* Qb  = (bf16*)d_out;                      // d_out scratch (dead until final GEMM)
    bf16* Kb  = Qb + (size_t)S * HD;
    bf16* Vb  = Kb + (size_t)S * GD;
    bf16* VtG = Vb + (size_t)S * GD;

    const bool fast = ws_size >= 112 * MB;
    const float qscale = 0.08838834764831845f;

    hipFuncSetAttribute(reinterpret_cast<const void*>(&flash_fwd4),
                        hipFuncAttributeMaxDynamicSharedMemorySize, 81920);

    cast_f32_bf16<<<(S * D / 4 + 255) / 256, 256, 0, stream>>>(x, xb, S * D / 4);

    if (fast) {
        bf16* Wqkvt = (bf16*)(ws + 32 * MB);       // [6144][4096] bf16 = 48MB
        bf16* Wot   = (bf16*)(ws + 80 * MB);       // [4096][4096] bf16 = 32MB

        transpose_to_bf16<true><<<dim3(HD / 256, D / 64), 256, 0, stream>>>(Wq, Wqkvt, D, HD);
        transpose_to_bf16<true><<<dim3(GD / 256, D / 64), 256, 0, stream>>>(Wk, Wqkvt + (size_t)HD * D, D, GD);
        transpose_to_bf16<true><<<dim3(GD / 256, D / 64), 256, 0, stream>>>(Wv, Wqkvt + (size_t)(HD + GD) * D, D, GD);
        transpose_to_bf16<true><<<dim3(D / 256, HD / 64), 256, 0, stream>>>(Wo, Wot, HD, D);

        hipFuncSetAttribute(reinterpret_cast<const void*>(&gemm192),
                            hipFuncAttributeMaxDynamicSharedMemorySize, 114688);
        hipFuncSetAttribute(reinterpret_cast<const void*>(&gemm3b),
                            hipFuncAttributeMaxDynamicSharedMemorySize, 147456);

        // QKV: 256x192 tiles -> 8x32 = 256 blocks = 1/CU
        gemm192<<<256, 512, 114688, stream>>>(xb, Wqkvt, Qb, Kb, Vb, D);

        rope_inplace<<<(S * HD / 2 + 255) / 256, 256, 0, stream>>>(Qb, cosT, sinT, HD, S * HD / 2, qscale);
        rope_inplace<<<(S * GD / 2 + 255) / 256, 256, 0, stream>>>(Kb, cosT, sinT, GD, S * GD / 2, 1.0f);

        transpose_to_bf16<false><<<dim3(GD / 256, S / 64), 256, 0, stream>>>(Vb, VtG, S, GD);

        flash_fwd4<<<NQT * H, 512, 81920, stream>>>(Qb, Kb, VtG, ctx);

        // Wo: 256x128 tiles, 8x32 = 256 blocks
        gemm3b<<<256, 512, 147456, stream>>>(ctx, Wot, out, D, HD, 32);
    } else {
        gemm_aBf16<true><<<dim3(HD / BN, S / BM, 1), 256, 0, stream>>>(
            xb, Wq, Wq, (void*)Qb, (void*)Qb, S, HD, D);
        gemm_aBf16<true><<<dim3(GD / BN, S / BM, 2), 256, 0, stream>>>(
            xb, Wk, Wv, (void*)Kb, (void*)Vb, S, GD, D);

        rope_inplace<<<(S * HD / 2 + 255) / 256, 256, 0, stream>>>(Qb, cosT, sinT, HD, S * HD / 2, qscale);
        rope_inplace<<<(S * GD / 2 + 255) / 256, 256, 0, stream>>>(Kb, cosT, sinT, GD, S * GD / 2, 1.0f);

        transpose_to_bf16<false><<<dim3(GD / 256, S / 64), 256, 0, stream>>>(Vb, VtG, S, GD);

        flash_fwd4<<<NQT * H, 512, 81920, stream>>>(Qb, Kb, VtG, ctx);

        gemm_aBf16<false><<<dim3(D / BN, S / BM, 1), 256, 0, stream>>>(
            ctx, Wo, Wo, (void*)out, (void*)out, S, D, HD);
    }

    (void)in_sizes; (void)n_in; (void)out_size; (void)ws_size;
}

// Round 8
// 350.657 us; speedup vs baseline: 1.1788x; 1.0441x over previous
//
#include <hip/hip_runtime.h>
#include <hip/hip_bf16.h>
#include <cstdint>
#include <cstddef>

#define S 2048
#define D 4096
#define H 32
#define G 8
#define DH 128
#define HD (H*DH)   // 4096
#define GD (G*DH)   // 1024

typedef __bf16 bf16;
typedef __bf16 bf16x4 __attribute__((ext_vector_type(4)));
typedef __bf16 bf16x8 __attribute__((ext_vector_type(8)));
typedef float f32x4 __attribute__((ext_vector_type(4)));

__device__ __forceinline__ void gload16(const void* g, void* l) {
    __builtin_amdgcn_global_load_lds(
        (const __attribute__((address_space(1))) void*)g,
        (__attribute__((address_space(3))) void*)l, 16, 0, 0);
}

#define FENCE() asm volatile("" ::: "memory")
#define BARRIER() do { FENCE(); __builtin_amdgcn_s_barrier(); FENCE(); } while (0)
#define VMCNT(n)  asm volatile("s_waitcnt vmcnt(" #n ")" ::: "memory")
#define LGKM0()   do { asm volatile("s_waitcnt lgkmcnt(0)" ::: "memory"); \
                       __builtin_amdgcn_sched_barrier(0); } while (0)

// ---------------------------------------------------------------- cast x -> bf16
__global__ __launch_bounds__(256) void cast_f32_bf16(const float* __restrict__ in,
                                                     bf16* __restrict__ out, int n4)
{
    int i = blockIdx.x * 256 + threadIdx.x;
    if (i < n4) {
        float4 v = reinterpret_cast<const float4*>(in)[i];
        bf16x4 o = { (bf16)v.x, (bf16)v.y, (bf16)v.z, (bf16)v.w };
        reinterpret_cast<bf16x4*>(out)[i] = o;
    }
}

// ---------------------------------------------------------------- transpose -> bf16
template<bool IN_F32>
__global__ __launch_bounds__(256) void transpose_to_bf16(
    const void* __restrict__ in, bf16* __restrict__ out, int R, int C)
{
    const int r0 = blockIdx.y * 64 + (threadIdx.x & 7) * 8;
    const int c0 = blockIdx.x * 256 + (threadIdx.x >> 3) * 8;
    bf16 m[8][8];
    #pragma unroll
    for (int j = 0; j < 8; ++j) {
        if constexpr (IN_F32) {
            const float* p = (const float*)in + (size_t)(r0 + j) * C + c0;
            float4 a = *reinterpret_cast<const float4*>(p);
            float4 b = *reinterpret_cast<const float4*>(p + 4);
            m[j][0] = (bf16)a.x; m[j][1] = (bf16)a.y; m[j][2] = (bf16)a.z; m[j][3] = (bf16)a.w;
            m[j][4] = (bf16)b.x; m[j][5] = (bf16)b.y; m[j][6] = (bf16)b.z; m[j][7] = (bf16)b.w;
        } else {
            const bf16* p = (const bf16*)in + (size_t)(r0 + j) * C + c0;
            bf16x8 v = *reinterpret_cast<const bf16x8*>(p);
            #pragma unroll
            for (int i = 0; i < 8; ++i) m[j][i] = v[i];
        }
    }
    #pragma unroll
    for (int i = 0; i < 8; ++i) {
        bf16x8 ov;
        #pragma unroll
        for (int j = 0; j < 8; ++j) ov[j] = m[j][i];
        *reinterpret_cast<bf16x8*>(out + (size_t)(c0 + i) * R + r0) = ov;
    }
}

// ---------------------------------------------------------------- RoPE in-place (+scale)
__global__ __launch_bounds__(256) void rope_inplace(bf16* __restrict__ Y,
                                                    const float* __restrict__ cosT,
                                                    const float* __restrict__ sinT,
                                                    int ncols, int total, float scale)
{
    int idx = blockIdx.x * 256 + threadIdx.x;
    if (idx >= total) return;
    int pairs = ncols >> 1;
    int s = idx / pairs;
    int p = idx - s * pairs;
    int head = p >> 6;
    int d = p & 63;
    size_t base = (size_t)s * ncols + head * DH;
    float c  = cosT[s * DH + d];
    float sn = sinT[s * DH + d];
    float a = (float)Y[base + d];
    float b = (float)Y[base + d + 64];
    Y[base + d]      = (bf16)((a * c - b * sn) * scale);
    Y[base + d + 64] = (bf16)((b * c + a * sn) * scale);
}

// ================================================================ QKV GEMM (r4 8-phase 256x256)
// Blocks [0,192): C[2048,6144] = A @ Bt, 256x256 tile, BK=64, 2 LDS bufs (64KB),
// 8 waves (2Mx4N, per-wave 128x64), r4-verified 8-phase schedule (118us, 48% active-CU
// MfmaUtil). Blocks [192,256): fused Wo [4096][4096] f32 -> Wot [4096][4096] bf16
// transpose on the otherwise-idle CUs (N=6144 gives only 24 column tiles).
__global__ __launch_bounds__(512) void gemm8p(
    const bf16* __restrict__ A, const bf16* __restrict__ Bt,
    bf16* __restrict__ Qout, bf16* __restrict__ Kout, bf16* __restrict__ Vout,
    const float* __restrict__ WoIn, bf16* __restrict__ WotOut,
    int N, int K, int nbn, int ngemm)
{
    extern __shared__ char smem[];   // buf d: A @ d*65536, B @ d*65536+32768
    const int tid = threadIdx.x;

    if ((int)blockIdx.x >= ngemm) {
        // ---- fused Wo transpose: 64 blocks x 512 threads, 8 col-passes
        const int tb = blockIdx.x - ngemm;               // 0..63
        const int r0 = tb * 64 + (tid & 7) * 8;          // rows of Wo (HD dim)
        #pragma unroll 1
        for (int pass = 0; pass < 8; ++pass) {
            const int c0 = pass * 512 + (tid >> 3) * 8;  // cols of Wo (D dim)
            bf16 m[8][8];
            #pragma unroll
            for (int j = 0; j < 8; ++j) {
                const float* p = WoIn + (size_t)(r0 + j) * D + c0;
                float4 a = *reinterpret_cast<const float4*>(p);
                float4 b = *reinterpret_cast<const float4*>(p + 4);
                m[j][0] = (bf16)a.x; m[j][1] = (bf16)a.y; m[j][2] = (bf16)a.z; m[j][3] = (bf16)a.w;
                m[j][4] = (bf16)b.x; m[j][5] = (bf16)b.y; m[j][6] = (bf16)b.z; m[j][7] = (bf16)b.w;
            }
            #pragma unroll
            for (int i = 0; i < 8; ++i) {
                bf16x8 ov;
                #pragma unroll
                for (int j = 0; j < 8; ++j) ov[j] = m[j][i];
                *reinterpret_cast<bf16x8*>(WotOut + (size_t)(c0 + i) * HD + r0) = ov;
            }
        }
        return;
    }

    const int lane = tid & 63, wave = tid >> 6;
    const int wr = wave >> 2, wc = wave & 3;
    const int l15 = lane & 15, lhi = lane >> 4;
    const int r8 = lane >> 3, c8 = lane & 7;
    const int csw = ((c8 ^ r8) << 3);          // pre-swizzled source chunk (elems)

    const int qq = ngemm >> 3;
    const int swz = (blockIdx.x & 7) * qq + (blockIdx.x >> 3);
    const int bm = (swz / nbn) * 256, bn = (swz % nbn) * 256;
    const int NT = K >> 6;

    auto stageA = [&](int buf, int h, int t) {
        #pragma unroll
        for (int L = 0; L < 2; ++L) {
            int row0 = L * 128 + h * 64 + wave * 8;
            gload16(A + (size_t)(bm + row0 + r8) * K + (t << 6) + csw,
                    smem + buf * 65536 + row0 * 128);
        }
    };
    auto stageB = [&](int buf, int h, int t) {
        #pragma unroll
        for (int L = 0; L < 2; ++L) {
            int row0 = h * 128 + L * 64 + wave * 8;
            gload16(Bt + (size_t)(bn + row0 + r8) * K + (t << 6) + csw,
                    smem + buf * 65536 + 32768 + row0 * 128);
        }
    };
    auto rdA = [&](const char* Ab, int mh, int ks, bf16x8* af) {
        #pragma unroll
        for (int m = 0; m < 4; ++m) {
            int row = wr * 128 + mh * 64 + m * 16 + l15;
            int ch = (ks * 4 + lhi) ^ (l15 & 7);
            af[m] = *reinterpret_cast<const bf16x8*>(Ab + row * 128 + ch * 16);
        }
    };
    auto rdB = [&](const char* Bb, int ks, bf16x8* bfv) {
        #pragma unroll
        for (int n = 0; n < 4; ++n) {
            int row = wc * 64 + n * 16 + l15;
            int ch = (ks * 4 + lhi) ^ (l15 & 7);
            bfv[n] = *reinterpret_cast<const bf16x8*>(Bb + row * 128 + ch * 16);
        }
    };

    f32x4 acc[8][4] = {};

    auto mm = [&](int mh, const bf16x8* af, const bf16x8* bfv) {
        LGKM0();
        __builtin_amdgcn_s_setprio(1);
        #pragma unroll
        for (int m = 0; m < 4; ++m)
            #pragma unroll
            for (int n = 0; n < 4; ++n)
                acc[mh * 4 + m][n] = __builtin_amdgcn_mfma_f32_16x16x32_bf16(
                    af[m], bfv[n], acc[mh * 4 + m][n], 0, 0, 0);
        __builtin_amdgcn_s_setprio(0);
    };

    // prologue: tile0 -> buf0 (all 4 units) + Ah'0(tile1) -> buf1
    stageA(0, 0, 0); stageA(0, 1, 0); stageB(0, 0, 0); stageB(0, 1, 0);
    stageA(1, 0, 1);
    VMCNT(2);
    BARRIER();

    const char* A0 = smem;
    const char* B0 = smem + 32768;
    const char* A1 = smem + 65536;
    const char* B1 = smem + 65536 + 32768;

    for (int j = 0; j < (NT >> 1); ++j) {
        const int tb = 2 * j + 1;
        const int t2 = (2 * j + 2 < NT) ? 2 * j + 2 : NT - 1;
        const int t3 = (2 * j + 3 < NT) ? 2 * j + 3 : NT - 1;
        bf16x8 af[4], bk0[4], bk1[4];

        // ---- tile a (buf0)
        rdB(B0, 0, bk0); rdA(A0, 0, 0, af);
        stageA(1, 1, tb);
        mm(0, af, bk0);
        BARRIER();

        rdB(B0, 1, bk1); rdA(A0, 0, 1, af);
        stageB(1, 0, tb);
        mm(0, af, bk1);
        BARRIER();

        rdA(A0, 1, 0, af);
        stageB(1, 1, tb);
        mm(1, af, bk0);
        BARRIER();

        rdA(A0, 1, 1, af);
        stageA(0, 0, t2);
        VMCNT(2);
        mm(1, af, bk1);
        BARRIER();

        // ---- tile b (buf1)
        rdB(B1, 0, bk0); rdA(A1, 0, 0, af);
        stageA(0, 1, t2);
        mm(0, af, bk0);
        BARRIER();

        rdB(B1, 1, bk1); rdA(A1, 0, 1, af);
        stageB(0, 0, t2);
        mm(0, af, bk1);
        BARRIER();

        rdA(A1, 1, 0, af);
        stageB(0, 1, t2);
        mm(1, af, bk0);
        BARRIER();

        rdA(A1, 1, 1, af);
        stageA(1, 0, t3);
        VMCNT(2);
        mm(1, af, bk1);
        BARRIER();
    }

    #pragma unroll
    for (int m = 0; m < 8; ++m) {
        int r0 = bm + wr * 128 + m * 16 + lhi * 4;
        #pragma unroll
        for (int n = 0; n < 4; ++n) {
            int c = bn + wc * 64 + n * 16 + l15;
            #pragma unroll
            for (int j = 0; j < 4; ++j) {
                bf16 v = (bf16)acc[m][n][j];
                if (bn < HD)
                    Qout[(size_t)(r0 + j) * HD + c] = v;
                else if (bn < HD + GD)
                    Kout[(size_t)(r0 + j) * GD + (c - HD)] = v;
                else
                    Vout[(size_t)(r0 + j) * GD + (c - HD - GD)] = v;
            }
        }
    }
}

// ================================================================ Wo GEMM: 256x128, 3-buf (r4 form)
// 256 blocks = 1/CU. BK=64, 3 bufs x 48KB. 8 waves (4Mx2N, per-wave 64x64),
// 2 phases/tile, stage t+2 into (t+2)%3, single vmcnt(6)+barrier per tile
// (3-buf FIFO: the 6 left outstanding are exactly t+2's -> t+1 proven landed).
__global__ __launch_bounds__(512, 2) void gemm3b(
    const bf16* __restrict__ A, const bf16* __restrict__ Bt,
    float* __restrict__ C, int N, int K, int nbn)
{
    extern __shared__ char smem[];   // buf b @ b*49152: A 32KB, B @ +32768 (16KB)
    const int tid = threadIdx.x, lane = tid & 63, wave = tid >> 6;
    const int wr = wave >> 1, wc = wave & 1;
    const int l15 = lane & 15, lhi = lane >> 4;
    const int r8 = lane >> 3, c8 = lane & 7;
    const int csw = ((c8 ^ r8) << 3);

    const int nwg = gridDim.x, qq = nwg >> 3;
    const int swz = (blockIdx.x & 7) * qq + (blockIdx.x >> 3);
    const int bm = (swz / nbn) * 256, bn = (swz % nbn) * 128;
    const int NT = K >> 6;

    auto stageA = [&](int buf, int L, int t) {
        int row0 = L * 64 + wave * 8;
        gload16(A + (size_t)(bm + row0 + r8) * K + (t << 6) + csw,
                smem + buf * 49152 + row0 * 128);
    };
    auto stageB = [&](int buf, int L, int t) {
        int row0 = L * 64 + wave * 8;
        gload16(Bt + (size_t)(bn + row0 + r8) * K + (t << 6) + csw,
                smem + buf * 49152 + 32768 + row0 * 128);
    };
    auto rdA = [&](const char* Ab, int ks, bf16x8* af) {
        #pragma unroll
        for (int m = 0; m < 4; ++m) {
            int row = wr * 64 + m * 16 + l15;
            int ch = (ks * 4 + lhi) ^ (l15 & 7);
            af[m] = *reinterpret_cast<const bf16x8*>(Ab + row * 128 + ch * 16);
        }
    };
    auto rdB = [&](const char* Bb, int ks, bf16x8* bfv) {
        #pragma unroll
        for (int n = 0; n < 4; ++n) {
            int row = wc * 64 + n * 16 + l15;
            int ch = (ks * 4 + lhi) ^ (l15 & 7);
            bfv[n] = *reinterpret_cast<const bf16x8*>(Bb + row * 128 + ch * 16);
        }
    };

    f32x4 acc[4][4] = {};

    // prologue: tile0 -> buf0, tile1 -> buf1
    #pragma unroll
    for (int L = 0; L < 4; ++L) stageA(0, L, 0);
    stageB(0, 0, 0); stageB(0, 1, 0);
    #pragma unroll
    for (int L = 0; L < 4; ++L) stageA(1, L, (1 < NT) ? 1 : 0);
    stageB(1, 0, (1 < NT) ? 1 : 0); stageB(1, 1, (1 < NT) ? 1 : 0);
    VMCNT(6);
    BARRIER();

    for (int t = 0; t < NT; ++t) {
        const char* Ab = smem + (t % 3) * 49152;
        const char* Bb = Ab + 32768;
        const int b2 = (t + 2) % 3;
        const int st = (t + 2 < NT) ? t + 2 : NT - 1;
        bf16x8 af[4], bk[4];

        // phase ks0
        rdB(Bb, 0, bk); rdA(Ab, 0, af);
        stageA(b2, 0, st); stageA(b2, 1, st);
        LGKM0();
        __builtin_amdgcn_s_setprio(1);
        #pragma unroll
        for (int m = 0; m < 4; ++m)
            #pragma unroll
            for (int n = 0; n < 4; ++n)
                acc[m][n] = __builtin_amdgcn_mfma_f32_16x16x32_bf16(af[m], bk[n], acc[m][n], 0, 0, 0);
        __builtin_amdgcn_s_setprio(0);

        // phase ks1
        rdB(Bb, 1, bk); rdA(Ab, 1, af);
        stageA(b2, 2, st); stageA(b2, 3, st);
        stageB(b2, 0, st); stageB(b2, 1, st);
        LGKM0();
        __builtin_amdgcn_s_setprio(1);
        #pragma unroll
        for (int m = 0; m < 4; ++m)
            #pragma unroll
            for (int n = 0; n < 4; ++n)
                acc[m][n] = __builtin_amdgcn_mfma_f32_16x16x32_bf16(af[m], bk[n], acc[m][n], 0, 0, 0);
        __builtin_amdgcn_s_setprio(0);

        VMCNT(6);
        BARRIER();
    }

    #pragma unroll
    for (int m = 0; m < 4; ++m) {
        int r0 = bm + wr * 64 + m * 16 + lhi * 4;
        #pragma unroll
        for (int n = 0; n < 4; ++n) {
            int c = bn + wc * 64 + n * 16 + l15;
            #pragma unroll
            for (int j = 0; j < 4; ++j)
                C[(size_t)(r0 + j) * N + c] = acc[m][n][j];
        }
    }
}

// ---------------------------------------------------------------- fallback GEMM (round-1)
#define BM 128
#define BN 128
#define BK 32
#define LDSK 40

template<bool OUT_BF16>
__global__ __launch_bounds__(256) void gemm_aBf16(
    const bf16* __restrict__ A,
    const float* __restrict__ B0, const float* __restrict__ B1,
    void* __restrict__ C0, void* __restrict__ C1,
    int M, int N, int K)
{
    __shared__ alignas(16) bf16 Al[BM][LDSK];
    __shared__ alignas(16) bf16 Bt[BN][LDSK];

    const float* __restrict__ B = blockIdx.z ? B1 : B0;
    void* __restrict__ C = blockIdx.z ? C1 : C0;

    const int tid  = threadIdx.x;
    const int lane = tid & 63;
    const int wave = tid >> 6;
    const int wm = (wave >> 1) * 64;
    const int wn = (wave & 1) * 64;
    const int bm = blockIdx.y * BM;
    const int bn = blockIdx.x * BN;
    const int l15 = lane & 15;
    const int lhi = lane >> 4;

    f32x4 acc[4][4] = {};

    for (int k0 = 0; k0 < K; k0 += BK) {
        #pragma unroll
        for (int it = 0; it < 2; ++it) {
            int idx = it * 256 + tid;
            int row = idx >> 2;
            int ko  = idx & 3;
            bf16x8 v = *reinterpret_cast<const bf16x8*>(
                A + (size_t)(bm + row) * K + k0 + ko * 8);
            *reinterpret_cast<bf16x8*>(&Al[row][ko * 8]) = v;
        }
        {
            int n = tid & 127;
            int kbase = (tid >> 7) * 8;
            const float* bp = B + (size_t)k0 * N + bn + n;
            #pragma unroll
            for (int half = 0; half < 2; ++half) {
                bf16x8 v;
                #pragma unroll
                for (int j = 0; j < 8; ++j)
                    v[j] = (bf16)bp[(size_t)(half * 16 + kbase + j) * N];
                *reinterpret_cast<bf16x8*>(&Bt[n][half * 16 + kbase]) = v;
            }
        }
        __syncthreads();

        bf16x8 af[4], bfv[4];
        #pragma unroll
        for (int m = 0; m < 4; ++m)
            af[m] = *reinterpret_cast<const bf16x8*>(&Al[wm + m * 16 + l15][lhi * 8]);
        #pragma unroll
        for (int n = 0; n < 4; ++n)
            bfv[n] = *reinterpret_cast<const bf16x8*>(&Bt[wn + n * 16 + l15][lhi * 8]);
        #pragma unroll
        for (int m = 0; m < 4; ++m)
            #pragma unroll
            for (int n = 0; n < 4; ++n)
                acc[m][n] = __builtin_amdgcn_mfma_f32_16x16x32_bf16(
                    af[m], bfv[n], acc[m][n], 0, 0, 0);
        __syncthreads();
    }

    #pragma unroll
    for (int m = 0; m < 4; ++m) {
        int r0 = bm + wm + m * 16 + lhi * 4;
        #pragma unroll
        for (int n = 0; n < 4; ++n) {
            int c = bn + wn + n * 16 + l15;
            #pragma unroll
            for (int j = 0; j < 4; ++j) {
                if constexpr (OUT_BF16)
                    reinterpret_cast<bf16*>(C)[(size_t)(r0 + j) * N + c] = (bf16)acc[m][n][j];
                else
                    reinterpret_cast<float*>(C)[(size_t)(r0 + j) * N + c] = acc[m][n][j];
            }
        }
    }
}

// ---------------------------------------------------------------- flash attention v4c
// 8 waves (512 thr), QBLK=128 (16 q-rows/wave), KVBLK=64, dbuf K/V (64KB) + P (16KB)
// = 80KB LDS -> 2 blocks/CU. Plain __launch_bounds__(512): r6's (512,4) forced
// VGPR=64 -> spills (FETCH 2.4x). Defer-max (T13, THR=8): keep m_old & skip the
// O-rescale when tile max grows <= 8 (also handles fully-masked tail tiles).
#define QBLK 128
#define KVBLK 64
#define NQT (S/QBLK)

template<bool MASK>
__device__ __forceinline__ void attn_tile(
    int t0, int q0, int wave, int l15, int lhi,
    const bf16x8* qf, const char* Kl, const char* Vl, char* Plw,
    f32x4* o, float* m_i, float* l_i)
{
    f32x4 sc[4] = {};
    __builtin_amdgcn_s_setprio(1);
    #pragma unroll
    for (int n = 0; n < 4; ++n) {
        int row = n * 16 + l15;
        #pragma unroll
        for (int kk = 0; kk < 4; ++kk) {
            bf16x8 kf = *reinterpret_cast<const bf16x8*>(
                Kl + row * 256 + ((((kk * 4 + lhi)) ^ (l15 & 7)) << 4));
            sc[n] = __builtin_amdgcn_mfma_f32_16x16x32_bf16(qf[kk], kf, sc[n], 0, 0, 0);
        }
    }
    __builtin_amdgcn_s_setprio(0);

    float corr[4];
    #pragma unroll
    for (int j = 0; j < 4; ++j) {
        const int qr = q0 + wave * 16 + lhi * 4 + j;
        float vals[4];
        float mx = -1e30f;
        #pragma unroll
        for (int n = 0; n < 4; ++n) {
            float v = sc[n][j];
            if constexpr (MASK) {
                int t = t0 + n * 16 + l15;
                if (t > qr) v = -1e30f;
            }
            vals[n] = v;
            mx = fmaxf(mx, v);
        }
        #pragma unroll
        for (int ms = 1; ms < 16; ms <<= 1)
            mx = fmaxf(mx, __shfl_xor(mx, ms, 16));
        // defer-max: keep old running max unless it grew by > 8
        float mnew, cr;
        if (mx <= m_i[j] + 8.0f) { mnew = m_i[j]; cr = 1.0f; }
        else                     { mnew = mx; cr = __expf(m_i[j] - mnew); }
        float rsum = 0.f;
        #pragma unroll
        for (int n = 0; n < 4; ++n) {
            float p = __expf(vals[n] - mnew);
            rsum += p;
            int r = lhi * 4 + j;
            int off = ((r << 7) + ((n * 16 + l15) << 1)) ^ ((r & 7) << 4);
            *reinterpret_cast<bf16*>(Plw + off) = (bf16)p;
        }
        #pragma unroll
        for (int ms = 1; ms < 16; ms <<= 1)
            rsum += __shfl_xor(rsum, ms, 16);
        l_i[j] = l_i[j] * cr + rsum;
        m_i[j] = mnew;
        corr[j] = cr;
    }

    if ((corr[0] != 1.f) | (corr[1] != 1.f) | (corr[2] != 1.f) | (corr[3] != 1.f)) {
        #pragma unroll
        for (int n = 0; n < 8; ++n)
            #pragma unroll
            for (int j = 0; j < 4; ++j)
                o[n][j] *= corr[j];
    }

    __builtin_amdgcn_s_setprio(1);
    #pragma unroll
    for (int kk = 0; kk < 2; ++kk) {
        bf16x8 pf = *reinterpret_cast<const bf16x8*>(
            Plw + (l15 << 7) + ((((kk * 4 + lhi)) ^ (l15 & 7)) << 4));
        #pragma unroll
        for (int n = 0; n < 8; ++n) {
            int d = n * 16 + l15;
            bf16x8 vf = *reinterpret_cast<const bf16x8*>(
                Vl + (d << 7) + ((((kk * 4 + lhi)) ^ (d & 7)) << 4));
            o[n] = __builtin_amdgcn_mfma_f32_16x16x32_bf16(pf, vf, o[n], 0, 0, 0);
        }
    }
    __builtin_amdgcn_s_setprio(0);
}

__global__ __launch_bounds__(512) void flash_fwd4(
    const bf16* __restrict__ Q, const bf16* __restrict__ Kr,
    const bf16* __restrict__ VtG, bf16* __restrict__ ctx)
{
    extern __shared__ char fsm[];   // buf b: K @ b*32768, V @ +16384; P @ 65536 (8x2KB)

    const int tid  = threadIdx.x;
    const int lane = tid & 63;
    const int wave = tid >> 6;
    const int l15 = lane & 15;
    const int lhi = lane >> 4;
    const int bid = blockIdx.x;
    const int qt = (NQT - 1) - (bid >> 5);               // longest tiles first
    const int h  = ((bid & 7) << 2) | ((bid >> 3) & 3);  // g == bid%8 == XCD
    const int g  = h >> 2;
    const int q0 = qt * QBLK;
    char* Plw = fsm + 65536 + wave * 2048;

    bf16x8 qf[4];
    {
        const bf16* qp = Q + (size_t)(q0 + wave * 16 + l15) * HD + h * DH + lhi * 8;
        #pragma unroll
        for (int kk = 0; kk < 4; ++kk)
            qf[kk] = *reinterpret_cast<const bf16x8*>(qp + kk * 32);
    }

    f32x4 o[8] = {};
    float m_i[4] = { -1e30f, -1e30f, -1e30f, -1e30f };
    float l_i[4] = {};

    auto stage = [&](int t0, int buf) {
        char* Kl = fsm + buf * 32768;
        char* Vl = Kl + 16384;
        #pragma unroll
        for (int t = 0; t < 2; ++t) {
            int ch = t * 512 + tid;
            {
                int row = ch >> 4, ci = ch & 15;
                gload16(Kr + (size_t)(t0 + row) * GD + g * DH + ((ci ^ (row & 7)) << 3),
                        Kl + ch * 16);
            }
            {
                int d = ch >> 3, ci = ch & 7;
                gload16(VtG + (size_t)(g * DH + d) * S + t0 + ((ci ^ (d & 7)) << 3),
                        Vl + ch * 16);
            }
        }
    };

    const int nt = 2 * qt + 2;
    stage(0, 0);
    VMCNT(0);
    BARRIER();

    for (int it = 0; it < nt; ++it) {
        if (it + 1 < nt) stage((it + 1) * KVBLK, (it + 1) & 1);
        const char* Kl = fsm + (it & 1) * 32768;
        const char* Vl = Kl + 16384;
        if (it >= nt - 2)
            attn_tile<true>(it * KVBLK, q0, wave, l15, lhi, qf, Kl, Vl, Plw, o, m_i, l_i);
        else
            attn_tile<false>(it * KVBLK, q0, wave, l15, lhi, qf, Kl, Vl, Plw, o, m_i, l_i);
        VMCNT(0);
        BARRIER();
    }

    #pragma unroll
    for (int n = 0; n < 8; ++n) {
        int c = h * DH + n * 16 + l15;
        #pragma unroll
        for (int j = 0; j < 4; ++j) {
            int r = q0 + wave * 16 + lhi * 4 + j;
            ctx[(size_t)r * HD + c] = (bf16)(o[n][j] / l_i[j]);
        }
    }
}

// ---------------------------------------------------------------- launch
extern "C" void kernel_launch(void* const* d_in, const int* in_sizes, int n_in,
                              void* d_out, int out_size, void* d_ws, size_t ws_size,
                              hipStream_t stream)
{
    const float* x    = (const float*)d_in[0];
    const float* cosT = (const float*)d_in[2];
    const float* sinT = (const float*)d_in[3];
    const float* Wq   = (const float*)d_in[4];
    const float* Wk   = (const float*)d_in[5];
    const float* Wv   = (const float*)d_in[6];
    const float* Wo   = (const float*)d_in[7];
    float* out = (float*)d_out;

    const size_t MB = (size_t)1 << 20;
    char* ws = (char*)d_ws;
    bf16* xb  = (bf16*)ws;                         // 16MB
    bf16* ctx = (bf16*)(ws + 16 * MB);             // 16MB
    bf16* Qb  = (bf16*)d_out;                      // d_out scratch (dead until final GEMM)
    bf16* Kb  = Qb + (size_t)S * HD;
    bf16* Vb  = Kb + (size_t)S * GD;
    bf16* VtG = Vb + (size_t)S * GD;

    const bool fast = ws_size >= 112 * MB;
    const float qscale = 0.08838834764831845f;

    hipFuncSetAttribute(reinterpret_cast<const void*>(&flash_fwd4),
                        hipFuncAttributeMaxDynamicSharedMemorySize, 81920);

    cast_f32_bf16<<<(S * D / 4 + 255) / 256, 256, 0, stream>>>(x, xb, S * D / 4);

    if (fast) {
        bf16* Wqkvt = (bf16*)(ws + 32 * MB);       // [6144][4096] bf16 = 48MB
        bf16* Wot   = (bf16*)(ws + 80 * MB);       // [4096][4096] bf16 = 32MB

        transpose_to_bf16<true><<<dim3(HD / 256, D / 64), 256, 0, stream>>>(Wq, Wqkvt, D, HD);
        transpose_to_bf16<true><<<dim3(GD / 256, D / 64), 256, 0, stream>>>(Wk, Wqkvt + (size_t)HD * D, D, GD);
        transpose_to_bf16<true><<<dim3(GD / 256, D / 64), 256, 0, stream>>>(Wv, Wqkvt + (size_t)(HD + GD) * D, D, GD);
        // Wo transpose is fused into gemm8p's spare 64 blocks

        hipFuncSetAttribute(reinterpret_cast<const void*>(&gemm8p),
                            hipFuncAttributeMaxDynamicSharedMemorySize, 131072);
        hipFuncSetAttribute(reinterpret_cast<const void*>(&gemm3b),
                            hipFuncAttributeMaxDynamicSharedMemorySize, 147456);

        // QKV: 192 GEMM blocks (8x24 of 256x256) + 64 Wo-transpose blocks = 256
        gemm8p<<<256, 512, 131072, stream>>>(
            xb, Wqkvt, Qb, Kb, Vb, Wo, Wot, HD + 2 * GD, D, 24, 192);

        rope_inplace<<<(S * HD / 2 + 255) / 256, 256, 0, stream>>>(Qb, cosT, sinT, HD, S * HD / 2, qscale);
        rope_inplace<<<(S * GD / 2 + 255) / 256, 256, 0, stream>>>(Kb, cosT, sinT, GD, S * GD / 2, 1.0f);

        transpose_to_bf16<false><<<dim3(GD / 256, S / 64), 256, 0, stream>>>(Vb, VtG, S, GD);

        flash_fwd4<<<NQT * H, 512, 81920, stream>>>(Qb, Kb, VtG, ctx);

        // Wo: 256x128 tiles, 8x32 = 256 blocks
        gemm3b<<<256, 512, 147456, stream>>>(ctx, Wot, out, D, HD, 32);
    } else {
        gemm_aBf16<true><<<dim3(HD / BN, S / BM, 1), 256, 0, stream>>>(
            xb, Wq, Wq, (void*)Qb, (void*)Qb, S, HD, D);
        gemm_aBf16<true><<<dim3(GD / BN, S / BM, 2), 256, 0, stream>>>(
            xb, Wk, Wv, (void*)Kb, (void*)Vb, S, GD, D);

        rope_inplace<<<(S * HD / 2 + 255) / 256, 256, 0, stream>>>(Qb, cosT, sinT, HD, S * HD / 2, qscale);
        rope_inplace<<<(S * GD / 2 + 255) / 256, 256, 0, stream>>>(Kb, cosT, sinT, GD, S * GD / 2, 1.0f);

        transpose_to_bf16<false><<<dim3(GD / 256, S / 64), 256, 0, stream>>>(Vb, VtG, S, GD);

        flash_fwd4<<<NQT * H, 512, 81920, stream>>>(Qb, Kb, VtG, ctx);

        gemm_aBf16<false><<<dim3(D / BN, S / BM, 1), 256, 0, stream>>>(
            ctx, Wo, Wo, (void*)out, (void*)out, S, D, HD);
    }

    (void)in_sizes; (void)n_in; (void)out_size; (void)ws_size;
}

// Round 9
// 345.196 us; speedup vs baseline: 1.1975x; 1.0158x over previous
//
#include <hip/hip_runtime.h>
#include <hip/hip_bf16.h>
#include <cstdint>
#include <cstddef>

#define S 2048
#define D 4096
#define H 32
#define G 8
#define DH 128
#define HD (H*DH)   // 4096
#define GD (G*DH)   // 1024

typedef __bf16 bf16;
typedef __bf16 bf16x4 __attribute__((ext_vector_type(4)));
typedef __bf16 bf16x8 __attribute__((ext_vector_type(8)));
typedef float f32x4 __attribute__((ext_vector_type(4)));

__device__ __forceinline__ void gload16(const void* g, void* l) {
    __builtin_amdgcn_global_load_lds(
        (const __attribute__((address_space(1))) void*)g,
        (__attribute__((address_space(3))) void*)l, 16, 0, 0);
}

#define FENCE() asm volatile("" ::: "memory")
#define BARRIER() do { FENCE(); __builtin_amdgcn_s_barrier(); FENCE(); } while (0)
#define VMCNT(n)  asm volatile("s_waitcnt vmcnt(" #n ")" ::: "memory")
#define LGKM0()   do { asm volatile("s_waitcnt lgkmcnt(0)" ::: "memory"); \
                       __builtin_amdgcn_sched_barrier(0); } while (0)

// ---------------------------------------------------------------- fused prep:
// blocks [0,512): cast x f32->bf16 (grid-stride float4)
// blocks [512,1536): Wq^T -> Wqkvt[0:4096]      (1024 blocks)
// blocks [1536,1792): Wk^T -> Wqkvt[4096:5120]  (256 blocks)
// blocks [1792,2048): Wv^T -> Wqkvt[5120:6144]  (256 blocks)
__global__ __launch_bounds__(256) void prep_fused(
    const float* __restrict__ x, bf16* __restrict__ xb,
    const float* __restrict__ Wq, const float* __restrict__ Wk,
    const float* __restrict__ Wv, bf16* __restrict__ Wqkvt)
{
    const int b = blockIdx.x, tid = threadIdx.x;
    if (b < 512) {
        int i = b * 4096 + tid;
        #pragma unroll
        for (int it = 0; it < 16; ++it, i += 256) {
            float4 v = reinterpret_cast<const float4*>(x)[i];
            bf16x4 o = { (bf16)v.x, (bf16)v.y, (bf16)v.z, (bf16)v.w };
            reinterpret_cast<bf16x4*>(xb)[i] = o;
        }
        return;
    }
    const float* in; bf16* out; int Cc, bx, by;
    if (b < 1536)      { int tb = b - 512;  in = Wq; out = Wqkvt;                       Cc = HD; bx = tb & 15; by = tb >> 4; }
    else if (b < 1792) { int tb = b - 1536; in = Wk; out = Wqkvt + (size_t)HD * D;      Cc = GD; bx = tb & 3;  by = tb >> 2; }
    else               { int tb = b - 1792; in = Wv; out = Wqkvt + (size_t)(HD+GD) * D; Cc = GD; bx = tb & 3;  by = tb >> 2; }
    const int r0 = by * 64 + (tid & 7) * 8;     // row in W (D dim)
    const int c0 = bx * 256 + (tid >> 3) * 8;   // col in W (N dim)
    bf16 m[8][8];
    #pragma unroll
    for (int j = 0; j < 8; ++j) {
        const float* p = in + (size_t)(r0 + j) * Cc + c0;
        float4 a = *reinterpret_cast<const float4*>(p);
        float4 bq = *reinterpret_cast<const float4*>(p + 4);
        m[j][0] = (bf16)a.x;  m[j][1] = (bf16)a.y;  m[j][2] = (bf16)a.z;  m[j][3] = (bf16)a.w;
        m[j][4] = (bf16)bq.x; m[j][5] = (bf16)bq.y; m[j][6] = (bf16)bq.z; m[j][7] = (bf16)bq.w;
    }
    #pragma unroll
    for (int i = 0; i < 8; ++i) {
        bf16x8 ov;
        #pragma unroll
        for (int j = 0; j < 8; ++j) ov[j] = m[j][i];
        *reinterpret_cast<bf16x8*>(out + (size_t)(c0 + i) * D + r0) = ov;
    }
}

// ---------------------------------------------------------------- fused rope + V^T:
// blocks [0,16384): rope Q (scale = 1/sqrt(DH) * log2(e), exp2-domain softmax)
// blocks [16384,20480): rope K (scale 1)
// blocks [20480,20608): transpose Vb [S][GD] -> VtG [GD][S]
__global__ __launch_bounds__(256) void rope_vt_fused(
    bf16* __restrict__ Qb, bf16* __restrict__ Kb,
    const bf16* __restrict__ Vb, bf16* __restrict__ VtG,
    const float* __restrict__ cosT, const float* __restrict__ sinT, float qs)
{
    const int b = blockIdx.x, tid = threadIdx.x;
    if (b < 20480) {
        bf16* Y; int ncols, idx; float scale;
        if (b < 16384) { Y = Qb; ncols = HD; idx = b * 256 + tid;           scale = qs; }
        else           { Y = Kb; ncols = GD; idx = (b - 16384) * 256 + tid; scale = 1.0f; }
        int pairs = ncols >> 1;
        int s = idx / pairs;
        int p = idx - s * pairs;
        int head = p >> 6;
        int d = p & 63;
        size_t base = (size_t)s * ncols + head * DH;
        float c  = cosT[s * DH + d];
        float sn = sinT[s * DH + d];
        float a = (float)Y[base + d];
        float bb = (float)Y[base + d + 64];
        Y[base + d]      = (bf16)((a * c - bb * sn) * scale);
        Y[base + d + 64] = (bf16)((bb * c + a * sn) * scale);
        return;
    }
    const int tb = b - 20480;
    const int r0 = (tb >> 2) * 64 + (tid & 7) * 8;    // S dim
    const int c0 = (tb & 3) * 256 + (tid >> 3) * 8;   // GD dim
    bf16 m[8][8];
    #pragma unroll
    for (int j = 0; j < 8; ++j) {
        bf16x8 v = *reinterpret_cast<const bf16x8*>(Vb + (size_t)(r0 + j) * GD + c0);
        #pragma unroll
        for (int i = 0; i < 8; ++i) m[j][i] = v[i];
    }
    #pragma unroll
    for (int i = 0; i < 8; ++i) {
        bf16x8 ov;
        #pragma unroll
        for (int j = 0; j < 8; ++j) ov[j] = m[j][i];
        *reinterpret_cast<bf16x8*>(VtG + (size_t)(c0 + i) * S + r0) = ov;
    }
}

// ---------------------------------------------------------------- standalone kernels (fallback path)
__global__ __launch_bounds__(256) void cast_f32_bf16(const float* __restrict__ in,
                                                     bf16* __restrict__ out, int n4)
{
    int i = blockIdx.x * 256 + threadIdx.x;
    if (i < n4) {
        float4 v = reinterpret_cast<const float4*>(in)[i];
        bf16x4 o = { (bf16)v.x, (bf16)v.y, (bf16)v.z, (bf16)v.w };
        reinterpret_cast<bf16x4*>(out)[i] = o;
    }
}

template<bool IN_F32>
__global__ __launch_bounds__(256) void transpose_to_bf16(
    const void* __restrict__ in, bf16* __restrict__ out, int R, int C)
{
    const int r0 = blockIdx.y * 64 + (threadIdx.x & 7) * 8;
    const int c0 = blockIdx.x * 256 + (threadIdx.x >> 3) * 8;
    bf16 m[8][8];
    #pragma unroll
    for (int j = 0; j < 8; ++j) {
        if constexpr (IN_F32) {
            const float* p = (const float*)in + (size_t)(r0 + j) * C + c0;
            float4 a = *reinterpret_cast<const float4*>(p);
            float4 b = *reinterpret_cast<const float4*>(p + 4);
            m[j][0] = (bf16)a.x; m[j][1] = (bf16)a.y; m[j][2] = (bf16)a.z; m[j][3] = (bf16)a.w;
            m[j][4] = (bf16)b.x; m[j][5] = (bf16)b.y; m[j][6] = (bf16)b.z; m[j][7] = (bf16)b.w;
        } else {
            const bf16* p = (const bf16*)in + (size_t)(r0 + j) * C + c0;
            bf16x8 v = *reinterpret_cast<const bf16x8*>(p);
            #pragma unroll
            for (int i = 0; i < 8; ++i) m[j][i] = v[i];
        }
    }
    #pragma unroll
    for (int i = 0; i < 8; ++i) {
        bf16x8 ov;
        #pragma unroll
        for (int j = 0; j < 8; ++j) ov[j] = m[j][i];
        *reinterpret_cast<bf16x8*>(out + (size_t)(c0 + i) * R + r0) = ov;
    }
}

__global__ __launch_bounds__(256) void rope_inplace(bf16* __restrict__ Y,
                                                    const float* __restrict__ cosT,
                                                    const float* __restrict__ sinT,
                                                    int ncols, int total, float scale)
{
    int idx = blockIdx.x * 256 + threadIdx.x;
    if (idx >= total) return;
    int pairs = ncols >> 1;
    int s = idx / pairs;
    int p = idx - s * pairs;
    int head = p >> 6;
    int d = p & 63;
    size_t base = (size_t)s * ncols + head * DH;
    float c  = cosT[s * DH + d];
    float sn = sinT[s * DH + d];
    float a = (float)Y[base + d];
    float b = (float)Y[base + d + 64];
    Y[base + d]      = (bf16)((a * c - b * sn) * scale);
    Y[base + d + 64] = (bf16)((b * c + a * sn) * scale);
}

// ================================================================ QKV GEMM (r4 8-phase 256x256)
// Blocks [0,192): 256x256 tile, BK=64, 2 LDS bufs, 8 waves, r4-verified 8-phase
// schedule; counted vmcnt moved AFTER the MFMA cluster (drain hides under MFMA).
// Blocks [192,256): fused Wo f32 -> Wot bf16 transpose on the idle CUs.
__global__ __launch_bounds__(512) void gemm8p(
    const bf16* __restrict__ A, const bf16* __restrict__ Bt,
    bf16* __restrict__ Qout, bf16* __restrict__ Kout, bf16* __restrict__ Vout,
    const float* __restrict__ WoIn, bf16* __restrict__ WotOut,
    int N, int K, int nbn, int ngemm)
{
    extern __shared__ char smem[];   // buf d: A @ d*65536, B @ d*65536+32768
    const int tid = threadIdx.x;

    if ((int)blockIdx.x >= ngemm) {
        const int tb = blockIdx.x - ngemm;               // 0..63
        const int r0 = tb * 64 + (tid & 7) * 8;          // rows of Wo (HD dim)
        #pragma unroll 1
        for (int pass = 0; pass < 8; ++pass) {
            const int c0 = pass * 512 + (tid >> 3) * 8;  // cols of Wo (D dim)
            bf16 m[8][8];
            #pragma unroll
            for (int j = 0; j < 8; ++j) {
                const float* p = WoIn + (size_t)(r0 + j) * D + c0;
                float4 a = *reinterpret_cast<const float4*>(p);
                float4 b = *reinterpret_cast<const float4*>(p + 4);
                m[j][0] = (bf16)a.x; m[j][1] = (bf16)a.y; m[j][2] = (bf16)a.z; m[j][3] = (bf16)a.w;
                m[j][4] = (bf16)b.x; m[j][5] = (bf16)b.y; m[j][6] = (bf16)b.z; m[j][7] = (bf16)b.w;
            }
            #pragma unroll
            for (int i = 0; i < 8; ++i) {
                bf16x8 ov;
                #pragma unroll
                for (int j = 0; j < 8; ++j) ov[j] = m[j][i];
                *reinterpret_cast<bf16x8*>(WotOut + (size_t)(c0 + i) * HD + r0) = ov;
            }
        }
        return;
    }

    const int lane = tid & 63, wave = tid >> 6;
    const int wr = wave >> 2, wc = wave & 3;
    const int l15 = lane & 15, lhi = lane >> 4;
    const int r8 = lane >> 3, c8 = lane & 7;
    const int csw = ((c8 ^ r8) << 3);

    const int qq = ngemm >> 3;
    const int swz = (blockIdx.x & 7) * qq + (blockIdx.x >> 3);
    const int bm = (swz / nbn) * 256, bn = (swz % nbn) * 256;
    const int NT = K >> 6;

    auto stageA = [&](int buf, int h, int t) {
        #pragma unroll
        for (int L = 0; L < 2; ++L) {
            int row0 = L * 128 + h * 64 + wave * 8;
            gload16(A + (size_t)(bm + row0 + r8) * K + (t << 6) + csw,
                    smem + buf * 65536 + row0 * 128);
        }
    };
    auto stageB = [&](int buf, int h, int t) {
        #pragma unroll
        for (int L = 0; L < 2; ++L) {
            int row0 = h * 128 + L * 64 + wave * 8;
            gload16(Bt + (size_t)(bn + row0 + r8) * K + (t << 6) + csw,
                    smem + buf * 65536 + 32768 + row0 * 128);
        }
    };
    auto rdA = [&](const char* Ab, int mh, int ks, bf16x8* af) {
        #pragma unroll
        for (int m = 0; m < 4; ++m) {
            int row = wr * 128 + mh * 64 + m * 16 + l15;
            int ch = (ks * 4 + lhi) ^ (l15 & 7);
            af[m] = *reinterpret_cast<const bf16x8*>(Ab + row * 128 + ch * 16);
        }
    };
    auto rdB = [&](const char* Bb, int ks, bf16x8* bfv) {
        #pragma unroll
        for (int n = 0; n < 4; ++n) {
            int row = wc * 64 + n * 16 + l15;
            int ch = (ks * 4 + lhi) ^ (l15 & 7);
            bfv[n] = *reinterpret_cast<const bf16x8*>(Bb + row * 128 + ch * 16);
        }
    };

    f32x4 acc[8][4] = {};

    auto mm = [&](int mh, const bf16x8* af, const bf16x8* bfv) {
        LGKM0();
        __builtin_amdgcn_s_setprio(1);
        #pragma unroll
        for (int m = 0; m < 4; ++m)
            #pragma unroll
            for (int n = 0; n < 4; ++n)
                acc[mh * 4 + m][n] = __builtin_amdgcn_mfma_f32_16x16x32_bf16(
                    af[m], bfv[n], acc[mh * 4 + m][n], 0, 0, 0);
        __builtin_amdgcn_s_setprio(0);
    };

    stageA(0, 0, 0); stageA(0, 1, 0); stageB(0, 0, 0); stageB(0, 1, 0);
    stageA(1, 0, 1);
    VMCNT(2);
    BARRIER();

    const char* A0 = smem;
    const char* B0 = smem + 32768;
    const char* A1 = smem + 65536;
    const char* B1 = smem + 65536 + 32768;

    for (int j = 0; j < (NT >> 1); ++j) {
        const int tb = 2 * j + 1;
        const int t2 = (2 * j + 2 < NT) ? 2 * j + 2 : NT - 1;
        const int t3 = (2 * j + 3 < NT) ? 2 * j + 3 : NT - 1;
        bf16x8 af[4], bk0[4], bk1[4];

        // ---- tile a (buf0)
        rdB(B0, 0, bk0); rdA(A0, 0, 0, af);
        stageA(1, 1, tb);
        mm(0, af, bk0);
        BARRIER();

        rdB(B0, 1, bk1); rdA(A0, 0, 1, af);
        stageB(1, 0, tb);
        mm(0, af, bk1);
        BARRIER();

        rdA(A0, 1, 0, af);
        stageB(1, 1, tb);
        mm(1, af, bk0);
        BARRIER();

        rdA(A0, 1, 1, af);
        stageA(0, 0, t2);
        mm(1, af, bk1);
        VMCNT(2);                    // tile b landed; drain hid under the 16 MFMA
        BARRIER();

        // ---- tile b (buf1)
        rdB(B1, 0, bk0); rdA(A1, 0, 0, af);
        stageA(0, 1, t2);
        mm(0, af, bk0);
        BARRIER();

        rdB(B1, 1, bk1); rdA(A1, 0, 1, af);
        stageB(0, 0, t2);
        mm(0, af, bk1);
        BARRIER();

        rdA(A1, 1, 0, af);
        stageB(0, 1, t2);
        mm(1, af, bk0);
        BARRIER();

        rdA(A1, 1, 1, af);
        stageA(1, 0, t3);
        mm(1, af, bk1);
        VMCNT(2);                    // tile t2 landed
        BARRIER();
    }

    #pragma unroll
    for (int m = 0; m < 8; ++m) {
        int r0 = bm + wr * 128 + m * 16 + lhi * 4;
        #pragma unroll
        for (int n = 0; n < 4; ++n) {
            int c = bn + wc * 64 + n * 16 + l15;
            #pragma unroll
            for (int j = 0; j < 4; ++j) {
                bf16 v = (bf16)acc[m][n][j];
                if (bn < HD)
                    Qout[(size_t)(r0 + j) * HD + c] = v;
                else if (bn < HD + GD)
                    Kout[(size_t)(r0 + j) * GD + (c - HD)] = v;
                else
                    Vout[(size_t)(r0 + j) * GD + (c - HD - GD)] = v;
            }
        }
    }
}

// ================================================================ Wo GEMM: 256x128, 3-buf (r4 form)
__global__ __launch_bounds__(512, 2) void gemm3b(
    const bf16* __restrict__ A, const bf16* __restrict__ Bt,
    float* __restrict__ C, int N, int K, int nbn)
{
    extern __shared__ char smem[];   // buf b @ b*49152: A 32KB, B @ +32768 (16KB)
    const int tid = threadIdx.x, lane = tid & 63, wave = tid >> 6;
    const int wr = wave >> 1, wc = wave & 1;
    const int l15 = lane & 15, lhi = lane >> 4;
    const int r8 = lane >> 3, c8 = lane & 7;
    const int csw = ((c8 ^ r8) << 3);

    const int nwg = gridDim.x, qq = nwg >> 3;
    const int swz = (blockIdx.x & 7) * qq + (blockIdx.x >> 3);
    const int bm = (swz / nbn) * 256, bn = (swz % nbn) * 128;
    const int NT = K >> 6;

    auto stageA = [&](int buf, int L, int t) {
        int row0 = L * 64 + wave * 8;
        gload16(A + (size_t)(bm + row0 + r8) * K + (t << 6) + csw,
                smem + buf * 49152 + row0 * 128);
    };
    auto stageB = [&](int buf, int L, int t) {
        int row0 = L * 64 + wave * 8;
        gload16(Bt + (size_t)(bn + row0 + r8) * K + (t << 6) + csw,
                smem + buf * 49152 + 32768 + row0 * 128);
    };
    auto rdA = [&](const char* Ab, int ks, bf16x8* af) {
        #pragma unroll
        for (int m = 0; m < 4; ++m) {
            int row = wr * 64 + m * 16 + l15;
            int ch = (ks * 4 + lhi) ^ (l15 & 7);
            af[m] = *reinterpret_cast<const bf16x8*>(Ab + row * 128 + ch * 16);
        }
    };
    auto rdB = [&](const char* Bb, int ks, bf16x8* bfv) {
        #pragma unroll
        for (int n = 0; n < 4; ++n) {
            int row = wc * 64 + n * 16 + l15;
            int ch = (ks * 4 + lhi) ^ (l15 & 7);
            bfv[n] = *reinterpret_cast<const bf16x8*>(Bb + row * 128 + ch * 16);
        }
    };

    f32x4 acc[4][4] = {};

    #pragma unroll
    for (int L = 0; L < 4; ++L) stageA(0, L, 0);
    stageB(0, 0, 0); stageB(0, 1, 0);
    #pragma unroll
    for (int L = 0; L < 4; ++L) stageA(1, L, (1 < NT) ? 1 : 0);
    stageB(1, 0, (1 < NT) ? 1 : 0); stageB(1, 1, (1 < NT) ? 1 : 0);
    VMCNT(6);
    BARRIER();

    for (int t = 0; t < NT; ++t) {
        const char* Ab = smem + (t % 3) * 49152;
        const char* Bb = Ab + 32768;
        const int b2 = (t + 2) % 3;
        const int st = (t + 2 < NT) ? t + 2 : NT - 1;
        bf16x8 af[4], bk[4];

        rdB(Bb, 0, bk); rdA(Ab, 0, af);
        stageA(b2, 0, st); stageA(b2, 1, st);
        LGKM0();
        __builtin_amdgcn_s_setprio(1);
        #pragma unroll
        for (int m = 0; m < 4; ++m)
            #pragma unroll
            for (int n = 0; n < 4; ++n)
                acc[m][n] = __builtin_amdgcn_mfma_f32_16x16x32_bf16(af[m], bk[n], acc[m][n], 0, 0, 0);
        __builtin_amdgcn_s_setprio(0);

        rdB(Bb, 1, bk); rdA(Ab, 1, af);
        stageA(b2, 2, st); stageA(b2, 3, st);
        stageB(b2, 0, st); stageB(b2, 1, st);
        LGKM0();
        __builtin_amdgcn_s_setprio(1);
        #pragma unroll
        for (int m = 0; m < 4; ++m)
            #pragma unroll
            for (int n = 0; n < 4; ++n)
                acc[m][n] = __builtin_amdgcn_mfma_f32_16x16x32_bf16(af[m], bk[n], acc[m][n], 0, 0, 0);
        __builtin_amdgcn_s_setprio(0);

        VMCNT(6);
        BARRIER();
    }

    #pragma unroll
    for (int m = 0; m < 4; ++m) {
        int r0 = bm + wr * 64 + m * 16 + lhi * 4;
        #pragma unroll
        for (int n = 0; n < 4; ++n) {
            int c = bn + wc * 64 + n * 16 + l15;
            #pragma unroll
            for (int j = 0; j < 4; ++j)
                C[(size_t)(r0 + j) * N + c] = acc[m][n][j];
        }
    }
}

// ---------------------------------------------------------------- fallback GEMM (round-1)
#define BM 128
#define BN 128
#define BK 32
#define LDSK 40

template<bool OUT_BF16>
__global__ __launch_bounds__(256) void gemm_aBf16(
    const bf16* __restrict__ A,
    const float* __restrict__ B0, const float* __restrict__ B1,
    void* __restrict__ C0, void* __restrict__ C1,
    int M, int N, int K)
{
    __shared__ alignas(16) bf16 Al[BM][LDSK];
    __shared__ alignas(16) bf16 Bt[BN][LDSK];

    const float* __restrict__ B = blockIdx.z ? B1 : B0;
    void* __restrict__ C = blockIdx.z ? C1 : C0;

    const int tid  = threadIdx.x;
    const int lane = tid & 63;
    const int wave = tid >> 6;
    const int wm = (wave >> 1) * 64;
    const int wn = (wave & 1) * 64;
    const int bm = blockIdx.y * BM;
    const int bn = blockIdx.x * BN;
    const int l15 = lane & 15;
    const int lhi = lane >> 4;

    f32x4 acc[4][4] = {};

    for (int k0 = 0; k0 < K; k0 += BK) {
        #pragma unroll
        for (int it = 0; it < 2; ++it) {
            int idx = it * 256 + tid;
            int row = idx >> 2;
            int ko  = idx & 3;
            bf16x8 v = *reinterpret_cast<const bf16x8*>(
                A + (size_t)(bm + row) * K + k0 + ko * 8);
            *reinterpret_cast<bf16x8*>(&Al[row][ko * 8]) = v;
        }
        {
            int n = tid & 127;
            int kbase = (tid >> 7) * 8;
            const float* bp = B + (size_t)k0 * N + bn + n;
            #pragma unroll
            for (int half = 0; half < 2; ++half) {
                bf16x8 v;
                #pragma unroll
                for (int j = 0; j < 8; ++j)
                    v[j] = (bf16)bp[(size_t)(half * 16 + kbase + j) * N];
                *reinterpret_cast<bf16x8*>(&Bt[n][half * 16 + kbase]) = v;
            }
        }
        __syncthreads();

        bf16x8 af[4], bfv[4];
        #pragma unroll
        for (int m = 0; m < 4; ++m)
            af[m] = *reinterpret_cast<const bf16x8*>(&Al[wm + m * 16 + l15][lhi * 8]);
        #pragma unroll
        for (int n = 0; n < 4; ++n)
            bfv[n] = *reinterpret_cast<const bf16x8*>(&Bt[wn + n * 16 + l15][lhi * 8]);
        #pragma unroll
        for (int m = 0; m < 4; ++m)
            #pragma unroll
            for (int n = 0; n < 4; ++n)
                acc[m][n] = __builtin_amdgcn_mfma_f32_16x16x32_bf16(
                    af[m], bfv[n], acc[m][n], 0, 0, 0);
        __syncthreads();
    }

    #pragma unroll
    for (int m = 0; m < 4; ++m) {
        int r0 = bm + wm + m * 16 + lhi * 4;
        #pragma unroll
        for (int n = 0; n < 4; ++n) {
            int c = bn + wn + n * 16 + l15;
            #pragma unroll
            for (int j = 0; j < 4; ++j) {
                if constexpr (OUT_BF16)
                    reinterpret_cast<bf16*>(C)[(size_t)(r0 + j) * N + c] = (bf16)acc[m][n][j];
                else
                    reinterpret_cast<float*>(C)[(size_t)(r0 + j) * N + c] = acc[m][n][j];
            }
        }
    }
}

// ---------------------------------------------------------------- flash attention v5 (exp2 softmax)
// 8 waves (512 thr), QBLK=128, KVBLK=64, dbuf K/V + P = 80KB -> 2 blocks/CU.
// Q pre-scaled by (1/sqrt(DH))*log2(e) -> p = exp2(vals - m), bare v_exp_f32.
// Defer-max THR=8 (P bounded by 2^8=256, bf16-safe).
#define QBLK 128
#define KVBLK 64
#define NQT (S/QBLK)

template<bool MASK>
__device__ __forceinline__ void attn_tile(
    int t0, int q0, int wave, int l15, int lhi,
    const bf16x8* qf, const char* Kl, const char* Vl, char* Plw,
    f32x4* o, float* m_i, float* l_i)
{
    f32x4 sc[4] = {};
    __builtin_amdgcn_s_setprio(1);
    #pragma unroll
    for (int n = 0; n < 4; ++n) {
        int row = n * 16 + l15;
        #pragma unroll
        for (int kk = 0; kk < 4; ++kk) {
            bf16x8 kf = *reinterpret_cast<const bf16x8*>(
                Kl + row * 256 + ((((kk * 4 + lhi)) ^ (l15 & 7)) << 4));
            sc[n] = __builtin_amdgcn_mfma_f32_16x16x32_bf16(qf[kk], kf, sc[n], 0, 0, 0);
        }
    }
    __builtin_amdgcn_s_setprio(0);

    float corr[4];
    #pragma unroll
    for (int j = 0; j < 4; ++j) {
        const int qr = q0 + wave * 16 + lhi * 4 + j;
        float vals[4];
        float mx = -1e30f;
        #pragma unroll
        for (int n = 0; n < 4; ++n) {
            float v = sc[n][j];
            if constexpr (MASK) {
                int t = t0 + n * 16 + l15;
                if (t > qr) v = -1e30f;
            }
            vals[n] = v;
            mx = fmaxf(mx, v);
        }
        #pragma unroll
        for (int ms = 1; ms < 16; ms <<= 1)
            mx = fmaxf(mx, __shfl_xor(mx, ms, 16));
        float mnew, cr;
        if (mx <= m_i[j] + 8.0f) { mnew = m_i[j]; cr = 1.0f; }
        else                     { mnew = mx; cr = exp2f(m_i[j] - mnew); }
        float rsum = 0.f;
        #pragma unroll
        for (int n = 0; n < 4; ++n) {
            float p = exp2f(vals[n] - mnew);
            rsum += p;
            int r = lhi * 4 + j;
            int off = ((r << 7) + ((n * 16 + l15) << 1)) ^ ((r & 7) << 4);
            *reinterpret_cast<bf16*>(Plw + off) = (bf16)p;
        }
        #pragma unroll
        for (int ms = 1; ms < 16; ms <<= 1)
            rsum += __shfl_xor(rsum, ms, 16);
        l_i[j] = l_i[j] * cr + rsum;
        m_i[j] = mnew;
        corr[j] = cr;
    }

    if ((corr[0] != 1.f) | (corr[1] != 1.f) | (corr[2] != 1.f) | (corr[3] != 1.f)) {
        #pragma unroll
        for (int n = 0; n < 8; ++n)
            #pragma unroll
            for (int j = 0; j < 4; ++j)
                o[n][j] *= corr[j];
    }

    __builtin_amdgcn_s_setprio(1);
    #pragma unroll
    for (int kk = 0; kk < 2; ++kk) {
        bf16x8 pf = *reinterpret_cast<const bf16x8*>(
            Plw + (l15 << 7) + ((((kk * 4 + lhi)) ^ (l15 & 7)) << 4));
        #pragma unroll
        for (int n = 0; n < 8; ++n) {
            int d = n * 16 + l15;
            bf16x8 vf = *reinterpret_cast<const bf16x8*>(
                Vl + (d << 7) + ((((kk * 4 + lhi)) ^ (d & 7)) << 4));
            o[n] = __builtin_amdgcn_mfma_f32_16x16x32_bf16(pf, vf, o[n], 0, 0, 0);
        }
    }
    __builtin_amdgcn_s_setprio(0);
}

__global__ __launch_bounds__(512) void flash_fwd5(
    const bf16* __restrict__ Q, const bf16* __restrict__ Kr,
    const bf16* __restrict__ VtG, bf16* __restrict__ ctx)
{
    extern __shared__ char fsm[];   // buf b: K @ b*32768, V @ +16384; P @ 65536 (8x2KB)

    const int tid  = threadIdx.x;
    const int lane = tid & 63;
    const int wave = tid >> 6;
    const int l15 = lane & 15;
    const int lhi = lane >> 4;
    const int bid = blockIdx.x;
    const int qt = (NQT - 1) - (bid >> 5);               // longest tiles first
    const int h  = ((bid & 7) << 2) | ((bid >> 3) & 3);  // g == bid%8 == XCD
    const int g  = h >> 2;
    const int q0 = qt * QBLK;
    char* Plw = fsm + 65536 + wave * 2048;

    bf16x8 qf[4];
    {
        const bf16* qp = Q + (size_t)(q0 + wave * 16 + l15) * HD + h * DH + lhi * 8;
        #pragma unroll
        for (int kk = 0; kk < 4; ++kk)
            qf[kk] = *reinterpret_cast<const bf16x8*>(qp + kk * 32);
    }

    f32x4 o[8] = {};
    float m_i[4] = { -1e30f, -1e30f, -1e30f, -1e30f };
    float l_i[4] = {};

    auto stage = [&](int t0, int buf) {
        char* Kl = fsm + buf * 32768;
        char* Vl = Kl + 16384;
        #pragma unroll
        for (int t = 0; t < 2; ++t) {
            int ch = t * 512 + tid;
            {
                int row = ch >> 4, ci = ch & 15;
                gload16(Kr + (size_t)(t0 + row) * GD + g * DH + ((ci ^ (row & 7)) << 3),
                        Kl + ch * 16);
            }
            {
                int d = ch >> 3, ci = ch & 7;
                gload16(VtG + (size_t)(g * DH + d) * S + t0 + ((ci ^ (d & 7)) << 3),
                        Vl + ch * 16);
            }
        }
    };

    const int nt = 2 * qt + 2;
    stage(0, 0);
    VMCNT(0);
    BARRIER();

    for (int it = 0; it < nt; ++it) {
        if (it + 1 < nt) stage((it + 1) * KVBLK, (it + 1) & 1);
        const char* Kl = fsm + (it & 1) * 32768;
        const char* Vl = Kl + 16384;
        if (it >= nt - 2)
            attn_tile<true>(it * KVBLK, q0, wave, l15, lhi, qf, Kl, Vl, Plw, o, m_i, l_i);
        else
            attn_tile<false>(it * KVBLK, q0, wave, l15, lhi, qf, Kl, Vl, Plw, o, m_i, l_i);
        VMCNT(0);
        BARRIER();
    }

    #pragma unroll
    for (int n = 0; n < 8; ++n) {
        int c = h * DH + n * 16 + l15;
        #pragma unroll
        for (int j = 0; j < 4; ++j) {
            int r = q0 + wave * 16 + lhi * 4 + j;
            ctx[(size_t)r * HD + c] = (bf16)(o[n][j] / l_i[j]);
        }
    }
}

// ---------------------------------------------------------------- launch
extern "C" void kernel_launch(void* const* d_in, const int* in_sizes, int n_in,
                              void* d_out, int out_size, void* d_ws, size_t ws_size,
                              hipStream_t stream)
{
    const float* x    = (const float*)d_in[0];
    const float* cosT = (const float*)d_in[2];
    const float* sinT = (const float*)d_in[3];
    const float* Wq   = (const float*)d_in[4];
    const float* Wk   = (const float*)d_in[5];
    const float* Wv   = (const float*)d_in[6];
    const float* Wo   = (const float*)d_in[7];
    float* out = (float*)d_out;

    const size_t MB = (size_t)1 << 20;
    char* ws = (char*)d_ws;
    bf16* xb  = (bf16*)ws;                         // 16MB
    bf16* ctx = (bf16*)(ws + 16 * MB);             // 16MB
    bf16* Qb  = (bf16*)d_out;                      // d_out scratch (dead until final GEMM)
    bf16* Kb  = Qb + (size_t)S * HD;
    bf16* Vb  = Kb + (size_t)S * GD;
    bf16* VtG = Vb + (size_t)S * GD;

    const bool fast = ws_size >= 112 * MB;
    // 1/sqrt(128) * log2(e): exp2-domain softmax
    const float qscale = 0.08838834764831845f * 1.4426950408889634f;

    hipFuncSetAttribute(reinterpret_cast<const void*>(&flash_fwd5),
                        hipFuncAttributeMaxDynamicSharedMemorySize, 81920);

    if (fast) {
        bf16* Wqkvt = (bf16*)(ws + 32 * MB);       // [6144][4096] bf16 = 48MB
        bf16* Wot   = (bf16*)(ws + 80 * MB);       // [4096][4096] bf16 = 32MB

        hipFuncSetAttribute(reinterpret_cast<const void*>(&gemm8p),
                            hipFuncAttributeMaxDynamicSharedMemorySize, 131072);
        hipFuncSetAttribute(reinterpret_cast<const void*>(&gemm3b),
                            hipFuncAttributeMaxDynamicSharedMemorySize, 147456);

        // cast + Wq/Wk/Wv transposes in one launch
        prep_fused<<<2048, 256, 0, stream>>>(x, xb, Wq, Wk, Wv, Wqkvt);

        // QKV: 192 GEMM blocks + 64 Wo-transpose blocks
        gemm8p<<<256, 512, 131072, stream>>>(
            xb, Wqkvt, Qb, Kb, Vb, Wo, Wot, HD + 2 * GD, D, 24, 192);

        // rope(Q) + rope(K) + V^T in one launch
        rope_vt_fused<<<20608, 256, 0, stream>>>(Qb, Kb, Vb, VtG, cosT, sinT, qscale);

        flash_fwd5<<<NQT * H, 512, 81920, stream>>>(Qb, Kb, VtG, ctx);

        gemm3b<<<256, 512, 147456, stream>>>(ctx, Wot, out, D, HD, 32);
    } else {
        cast_f32_bf16<<<(S * D / 4 + 255) / 256, 256, 0, stream>>>(x, xb, S * D / 4);

        gemm_aBf16<true><<<dim3(HD / BN, S / BM, 1), 256, 0, stream>>>(
            xb, Wq, Wq, (void*)Qb, (void*)Qb, S, HD, D);
        gemm_aBf16<true><<<dim3(GD / BN, S / BM, 2), 256, 0, stream>>>(
            xb, Wk, Wv, (void*)Kb, (void*)Vb, S, GD, D);

        rope_inplace<<<(S * HD / 2 + 255) / 256, 256, 0, stream>>>(Qb, cosT, sinT, HD, S * HD / 2, qscale);
        rope_inplace<<<(S * GD / 2 + 255) / 256, 256, 0, stream>>>(Kb, cosT, sinT, GD, S * GD / 2, 1.0f);

        transpose_to_bf16<false><<<dim3(GD / 256, S / 64), 256, 0, stream>>>(Vb, VtG, S, GD);

        flash_fwd5<<<NQT * H, 512, 81920, stream>>>(Qb, Kb, VtG, ctx);

        gemm_aBf16<false><<<dim3(D / BN, S / BM, 1), 256, 0, stream>>>(
            ctx, Wo, Wo, (void*)out, (void*)out, S, D, HD);
    }

    (void)in_sizes; (void)n_in; (void)out_size; (void)ws_size;
}

// Round 10
// 336.229 us; speedup vs baseline: 1.2294x; 1.0267x over previous
//
#include <hip/hip_runtime.h>
#include <hip/hip_bf16.h>
#include <cstdint>
#include <cstddef>

#define S 2048
#define D 4096
#define H 32
#define G 8
#define DH 128
#define HD (H*DH)   // 4096
#define GD (G*DH)   // 1024

typedef __bf16 bf16;
typedef __bf16 bf16x4 __attribute__((ext_vector_type(4)));
typedef __bf16 bf16x8 __attribute__((ext_vector_type(8)));
typedef float f32x4 __attribute__((ext_vector_type(4)));

__device__ __forceinline__ void gload16(const void* g, void* l) {
    __builtin_amdgcn_global_load_lds(
        (const __attribute__((address_space(1))) void*)g,
        (__attribute__((address_space(3))) void*)l, 16, 0, 0);
}

#define FENCE() asm volatile("" ::: "memory")
#define BARRIER() do { FENCE(); __builtin_amdgcn_s_barrier(); FENCE(); } while (0)
#define VMCNT(n)  asm volatile("s_waitcnt vmcnt(" #n ")" ::: "memory")
#define LGKM0()   do { asm volatile("s_waitcnt lgkmcnt(0)" ::: "memory"); \
                       __builtin_amdgcn_sched_barrier(0); } while (0)

// ---------------------------------------------------------------- fused prep:
// blocks [0,512): cast x f32->bf16 ; [512,1536): Wq^T ; [1536,1792): Wk^T ; [1792,2048): Wv^T
__global__ __launch_bounds__(256) void prep_fused(
    const float* __restrict__ x, bf16* __restrict__ xb,
    const float* __restrict__ Wq, const float* __restrict__ Wk,
    const float* __restrict__ Wv, bf16* __restrict__ Wqkvt)
{
    const int b = blockIdx.x, tid = threadIdx.x;
    if (b < 512) {
        int i = b * 4096 + tid;
        #pragma unroll
        for (int it = 0; it < 16; ++it, i += 256) {
            float4 v = reinterpret_cast<const float4*>(x)[i];
            bf16x4 o = { (bf16)v.x, (bf16)v.y, (bf16)v.z, (bf16)v.w };
            reinterpret_cast<bf16x4*>(xb)[i] = o;
        }
        return;
    }
    const float* in; bf16* out; int Cc, bx, by;
    if (b < 1536)      { int tb = b - 512;  in = Wq; out = Wqkvt;                       Cc = HD; bx = tb & 15; by = tb >> 4; }
    else if (b < 1792) { int tb = b - 1536; in = Wk; out = Wqkvt + (size_t)HD * D;      Cc = GD; bx = tb & 3;  by = tb >> 2; }
    else               { int tb = b - 1792; in = Wv; out = Wqkvt + (size_t)(HD+GD) * D; Cc = GD; bx = tb & 3;  by = tb >> 2; }
    const int r0 = by * 64 + (tid & 7) * 8;
    const int c0 = bx * 256 + (tid >> 3) * 8;
    bf16 m[8][8];
    #pragma unroll
    for (int j = 0; j < 8; ++j) {
        const float* p = in + (size_t)(r0 + j) * Cc + c0;
        float4 a = *reinterpret_cast<const float4*>(p);
        float4 bq = *reinterpret_cast<const float4*>(p + 4);
        m[j][0] = (bf16)a.x;  m[j][1] = (bf16)a.y;  m[j][2] = (bf16)a.z;  m[j][3] = (bf16)a.w;
        m[j][4] = (bf16)bq.x; m[j][5] = (bf16)bq.y; m[j][6] = (bf16)bq.z; m[j][7] = (bf16)bq.w;
    }
    #pragma unroll
    for (int i = 0; i < 8; ++i) {
        bf16x8 ov;
        #pragma unroll
        for (int j = 0; j < 8; ++j) ov[j] = m[j][i];
        *reinterpret_cast<bf16x8*>(out + (size_t)(c0 + i) * D + r0) = ov;
    }
}

// ---------------------------------------------------------------- fused rope + V^T
__global__ __launch_bounds__(256) void rope_vt_fused(
    bf16* __restrict__ Qb, bf16* __restrict__ Kb,
    const bf16* __restrict__ Vb, bf16* __restrict__ VtG,
    const float* __restrict__ cosT, const float* __restrict__ sinT, float qs)
{
    const int b = blockIdx.x, tid = threadIdx.x;
    if (b < 20480) {
        bf16* Y; int ncols, idx; float scale;
        if (b < 16384) { Y = Qb; ncols = HD; idx = b * 256 + tid;           scale = qs; }
        else           { Y = Kb; ncols = GD; idx = (b - 16384) * 256 + tid; scale = 1.0f; }
        int pairs = ncols >> 1;
        int s = idx / pairs;
        int p = idx - s * pairs;
        int head = p >> 6;
        int d = p & 63;
        size_t base = (size_t)s * ncols + head * DH;
        float c  = cosT[s * DH + d];
        float sn = sinT[s * DH + d];
        float a = (float)Y[base + d];
        float bb = (float)Y[base + d + 64];
        Y[base + d]      = (bf16)((a * c - bb * sn) * scale);
        Y[base + d + 64] = (bf16)((bb * c + a * sn) * scale);
        return;
    }
    const int tb = b - 20480;
    const int r0 = (tb >> 2) * 64 + (tid & 7) * 8;
    const int c0 = (tb & 3) * 256 + (tid >> 3) * 8;
    bf16 m[8][8];
    #pragma unroll
    for (int j = 0; j < 8; ++j) {
        bf16x8 v = *reinterpret_cast<const bf16x8*>(Vb + (size_t)(r0 + j) * GD + c0);
        #pragma unroll
        for (int i = 0; i < 8; ++i) m[j][i] = v[i];
    }
    #pragma unroll
    for (int i = 0; i < 8; ++i) {
        bf16x8 ov;
        #pragma unroll
        for (int j = 0; j < 8; ++j) ov[j] = m[j][i];
        *reinterpret_cast<bf16x8*>(VtG + (size_t)(c0 + i) * S + r0) = ov;
    }
}

// ---------------------------------------------------------------- standalone kernels (fallback path)
__global__ __launch_bounds__(256) void cast_f32_bf16(const float* __restrict__ in,
                                                     bf16* __restrict__ out, int n4)
{
    int i = blockIdx.x * 256 + threadIdx.x;
    if (i < n4) {
        float4 v = reinterpret_cast<const float4*>(in)[i];
        bf16x4 o = { (bf16)v.x, (bf16)v.y, (bf16)v.z, (bf16)v.w };
        reinterpret_cast<bf16x4*>(out)[i] = o;
    }
}

template<bool IN_F32>
__global__ __launch_bounds__(256) void transpose_to_bf16(
    const void* __restrict__ in, bf16* __restrict__ out, int R, int C)
{
    const int r0 = blockIdx.y * 64 + (threadIdx.x & 7) * 8;
    const int c0 = blockIdx.x * 256 + (threadIdx.x >> 3) * 8;
    bf16 m[8][8];
    #pragma unroll
    for (int j = 0; j < 8; ++j) {
        if constexpr (IN_F32) {
            const float* p = (const float*)in + (size_t)(r0 + j) * C + c0;
            float4 a = *reinterpret_cast<const float4*>(p);
            float4 b = *reinterpret_cast<const float4*>(p + 4);
            m[j][0] = (bf16)a.x; m[j][1] = (bf16)a.y; m[j][2] = (bf16)a.z; m[j][3] = (bf16)a.w;
            m[j][4] = (bf16)b.x; m[j][5] = (bf16)b.y; m[j][6] = (bf16)b.z; m[j][7] = (bf16)b.w;
        } else {
            const bf16* p = (const bf16*)in + (size_t)(r0 + j) * C + c0;
            bf16x8 v = *reinterpret_cast<const bf16x8*>(p);
            #pragma unroll
            for (int i = 0; i < 8; ++i) m[j][i] = v[i];
        }
    }
    #pragma unroll
    for (int i = 0; i < 8; ++i) {
        bf16x8 ov;
        #pragma unroll
        for (int j = 0; j < 8; ++j) ov[j] = m[j][i];
        *reinterpret_cast<bf16x8*>(out + (size_t)(c0 + i) * R + r0) = ov;
    }
}

__global__ __launch_bounds__(256) void rope_inplace(bf16* __restrict__ Y,
                                                    const float* __restrict__ cosT,
                                                    const float* __restrict__ sinT,
                                                    int ncols, int total, float scale)
{
    int idx = blockIdx.x * 256 + threadIdx.x;
    if (idx >= total) return;
    int pairs = ncols >> 1;
    int s = idx / pairs;
    int p = idx - s * pairs;
    int head = p >> 6;
    int d = p & 63;
    size_t base = (size_t)s * ncols + head * DH;
    float c  = cosT[s * DH + d];
    float sn = sinT[s * DH + d];
    float a = (float)Y[base + d];
    float b = (float)Y[base + d + 64];
    Y[base + d]      = (bf16)((a * c - b * sn) * scale);
    Y[base + d + 64] = (bf16)((b * c + a * sn) * scale);
}

// ================================================================ QKV GEMM (r4 8-phase 256x256)
// Blocks [0,192): grid 8(M) x 24(N). 2D XCD regions: XCD x owns a 4-row x 6-col
// region (A-panel touched by 4 XCDs, B-panel by 2 -> device L2-miss ~164MB vs 237
// measured with 1x24 row-stripes). Blocks [192,256): fused Wo transpose.
__global__ __launch_bounds__(512) void gemm8p(
    const bf16* __restrict__ A, const bf16* __restrict__ Bt,
    bf16* __restrict__ Qout, bf16* __restrict__ Kout, bf16* __restrict__ Vout,
    const float* __restrict__ WoIn, bf16* __restrict__ WotOut,
    int N, int K, int ngemm)
{
    extern __shared__ char smem[];   // buf d: A @ d*65536, B @ d*65536+32768
    const int tid = threadIdx.x;

    if ((int)blockIdx.x >= ngemm) {
        const int tb = blockIdx.x - ngemm;               // 0..63
        const int r0 = tb * 64 + (tid & 7) * 8;
        #pragma unroll 1
        for (int pass = 0; pass < 8; ++pass) {
            const int c0 = pass * 512 + (tid >> 3) * 8;
            bf16 m[8][8];
            #pragma unroll
            for (int j = 0; j < 8; ++j) {
                const float* p = WoIn + (size_t)(r0 + j) * D + c0;
                float4 a = *reinterpret_cast<const float4*>(p);
                float4 b = *reinterpret_cast<const float4*>(p + 4);
                m[j][0] = (bf16)a.x; m[j][1] = (bf16)a.y; m[j][2] = (bf16)a.z; m[j][3] = (bf16)a.w;
                m[j][4] = (bf16)b.x; m[j][5] = (bf16)b.y; m[j][6] = (bf16)b.z; m[j][7] = (bf16)b.w;
            }
            #pragma unroll
            for (int i = 0; i < 8; ++i) {
                bf16x8 ov;
                #pragma unroll
                for (int j = 0; j < 8; ++j) ov[j] = m[j][i];
                *reinterpret_cast<bf16x8*>(WotOut + (size_t)(c0 + i) * HD + r0) = ov;
            }
        }
        return;
    }

    const int lane = tid & 63, wave = tid >> 6;
    const int wr = wave >> 2, wc = wave & 3;
    const int l15 = lane & 15, lhi = lane >> 4;
    const int r8 = lane >> 3, c8 = lane & 7;
    const int csw = ((c8 ^ r8) << 3);

    // 2D XCD region map: x = XCD, i = local index; region = 4 rows x 6 cols
    const int x = blockIdx.x & 7, i = blockIdx.x >> 3;
    const int brow = (x >> 2) * 4 + (i & 3);
    const int bcol = (x & 3) * 6 + (i >> 2);
    const int bm = brow * 256, bn = bcol * 256;
    const int NT = K >> 6;

    auto stageA = [&](int buf, int h, int t) {
        #pragma unroll
        for (int L = 0; L < 2; ++L) {
            int row0 = L * 128 + h * 64 + wave * 8;
            gload16(A + (size_t)(bm + row0 + r8) * K + (t << 6) + csw,
                    smem + buf * 65536 + row0 * 128);
        }
    };
    auto stageB = [&](int buf, int h, int t) {
        #pragma unroll
        for (int L = 0; L < 2; ++L) {
            int row0 = h * 128 + L * 64 + wave * 8;
            gload16(Bt + (size_t)(bn + row0 + r8) * K + (t << 6) + csw,
                    smem + buf * 65536 + 32768 + row0 * 128);
        }
    };
    auto rdA = [&](const char* Ab, int mh, int ks, bf16x8* af) {
        #pragma unroll
        for (int m = 0; m < 4; ++m) {
            int row = wr * 128 + mh * 64 + m * 16 + l15;
            int ch = (ks * 4 + lhi) ^ (l15 & 7);
            af[m] = *reinterpret_cast<const bf16x8*>(Ab + row * 128 + ch * 16);
        }
    };
    auto rdB = [&](const char* Bb, int ks, bf16x8* bfv) {
        #pragma unroll
        for (int n = 0; n < 4; ++n) {
            int row = wc * 64 + n * 16 + l15;
            int ch = (ks * 4 + lhi) ^ (l15 & 7);
            bfv[n] = *reinterpret_cast<const bf16x8*>(Bb + row * 128 + ch * 16);
        }
    };

    f32x4 acc[8][4] = {};

    auto mm = [&](int mh, const bf16x8* af, const bf16x8* bfv) {
        LGKM0();
        __builtin_amdgcn_s_setprio(1);
        #pragma unroll
        for (int m = 0; m < 4; ++m)
            #pragma unroll
            for (int n = 0; n < 4; ++n)
                acc[mh * 4 + m][n] = __builtin_amdgcn_mfma_f32_16x16x32_bf16(
                    af[m], bfv[n], acc[mh * 4 + m][n], 0, 0, 0);
        __builtin_amdgcn_s_setprio(0);
    };

    stageA(0, 0, 0); stageA(0, 1, 0); stageB(0, 0, 0); stageB(0, 1, 0);
    stageA(1, 0, 1);
    VMCNT(2);
    BARRIER();

    const char* A0 = smem;
    const char* B0 = smem + 32768;
    const char* A1 = smem + 65536;
    const char* B1 = smem + 65536 + 32768;

    for (int j = 0; j < (NT >> 1); ++j) {
        const int tb = 2 * j + 1;
        const int t2 = (2 * j + 2 < NT) ? 2 * j + 2 : NT - 1;
        const int t3 = (2 * j + 3 < NT) ? 2 * j + 3 : NT - 1;
        bf16x8 af[4], bk0[4], bk1[4];

        // ---- tile a (buf0)
        rdB(B0, 0, bk0); rdA(A0, 0, 0, af);
        stageA(1, 1, tb);
        mm(0, af, bk0);
        BARRIER();

        rdB(B0, 1, bk1); rdA(A0, 0, 1, af);
        stageB(1, 0, tb);
        mm(0, af, bk1);
        BARRIER();

        rdA(A0, 1, 0, af);
        stageB(1, 1, tb);
        mm(1, af, bk0);
        BARRIER();

        rdA(A0, 1, 1, af);
        stageA(0, 0, t2);
        mm(1, af, bk1);
        VMCNT(2);
        BARRIER();

        // ---- tile b (buf1)
        rdB(B1, 0, bk0); rdA(A1, 0, 0, af);
        stageA(0, 1, t2);
        mm(0, af, bk0);
        BARRIER();

        rdB(B1, 1, bk1); rdA(A1, 0, 1, af);
        stageB(0, 0, t2);
        mm(0, af, bk1);
        BARRIER();

        rdA(A1, 1, 0, af);
        stageB(0, 1, t2);
        mm(1, af, bk0);
        BARRIER();

        rdA(A1, 1, 1, af);
        stageA(1, 0, t3);
        mm(1, af, bk1);
        VMCNT(2);
        BARRIER();
    }

    #pragma unroll
    for (int m = 0; m < 8; ++m) {
        int r0 = bm + wr * 128 + m * 16 + lhi * 4;
        #pragma unroll
        for (int n = 0; n < 4; ++n) {
            int c = bn + wc * 64 + n * 16 + l15;
            #pragma unroll
            for (int j = 0; j < 4; ++j) {
                bf16 v = (bf16)acc[m][n][j];
                if (bn < HD)
                    Qout[(size_t)(r0 + j) * HD + c] = v;
                else if (bn < HD + GD)
                    Kout[(size_t)(r0 + j) * GD + (c - HD)] = v;
                else
                    Vout[(size_t)(r0 + j) * GD + (c - HD - GD)] = v;
            }
        }
    }
}

// ================================================================ Wo GEMM: 256x128, 3-buf
// Grid 8(M) x 32(N) = 256. 2D XCD regions: 4 rows x 8 cols per XCD
// (A-panel in 4 XCDs, B-panel in 2 -> ~128MB L2-miss vs ~272 with row-stripes).
__global__ __launch_bounds__(512, 2) void gemm3b(
    const bf16* __restrict__ A, const bf16* __restrict__ Bt,
    float* __restrict__ C, int N, int K)
{
    extern __shared__ char smem[];   // buf b @ b*49152: A 32KB, B @ +32768 (16KB)
    const int tid = threadIdx.x, lane = tid & 63, wave = tid >> 6;
    const int wr = wave >> 1, wc = wave & 1;
    const int l15 = lane & 15, lhi = lane >> 4;
    const int r8 = lane >> 3, c8 = lane & 7;
    const int csw = ((c8 ^ r8) << 3);

    const int x = blockIdx.x & 7, i = blockIdx.x >> 3;
    const int brow = (x >> 2) * 4 + (i & 3);
    const int bcol = (x & 3) * 8 + (i >> 2);
    const int bm = brow * 256, bn = bcol * 128;
    const int NT = K >> 6;

    auto stageA = [&](int buf, int L, int t) {
        int row0 = L * 64 + wave * 8;
        gload16(A + (size_t)(bm + row0 + r8) * K + (t << 6) + csw,
                smem + buf * 49152 + row0 * 128);
    };
    auto stageB = [&](int buf, int L, int t) {
        int row0 = L * 64 + wave * 8;
        gload16(Bt + (size_t)(bn + row0 + r8) * K + (t << 6) + csw,
                smem + buf * 49152 + 32768 + row0 * 128);
    };
    auto rdA = [&](const char* Ab, int ks, bf16x8* af) {
        #pragma unroll
        for (int m = 0; m < 4; ++m) {
            int row = wr * 64 + m * 16 + l15;
            int ch = (ks * 4 + lhi) ^ (l15 & 7);
            af[m] = *reinterpret_cast<const bf16x8*>(Ab + row * 128 + ch * 16);
        }
    };
    auto rdB = [&](const char* Bb, int ks, bf16x8* bfv) {
        #pragma unroll
        for (int n = 0; n < 4; ++n) {
            int row = wc * 64 + n * 16 + l15;
            int ch = (ks * 4 + lhi) ^ (l15 & 7);
            bfv[n] = *reinterpret_cast<const bf16x8*>(Bb + row * 128 + ch * 16);
        }
    };

    f32x4 acc[4][4] = {};

    #pragma unroll
    for (int L = 0; L < 4; ++L) stageA(0, L, 0);
    stageB(0, 0, 0); stageB(0, 1, 0);
    #pragma unroll
    for (int L = 0; L < 4; ++L) stageA(1, L, (1 < NT) ? 1 : 0);
    stageB(1, 0, (1 < NT) ? 1 : 0); stageB(1, 1, (1 < NT) ? 1 : 0);
    VMCNT(6);
    BARRIER();

    for (int t = 0; t < NT; ++t) {
        const char* Ab = smem + (t % 3) * 49152;
        const char* Bb = Ab + 32768;
        const int b2 = (t + 2) % 3;
        const int st = (t + 2 < NT) ? t + 2 : NT - 1;
        bf16x8 af[4], bk[4];

        rdB(Bb, 0, bk); rdA(Ab, 0, af);
        stageA(b2, 0, st); stageA(b2, 1, st);
        LGKM0();
        __builtin_amdgcn_s_setprio(1);
        #pragma unroll
        for (int m = 0; m < 4; ++m)
            #pragma unroll
            for (int n = 0; n < 4; ++n)
                acc[m][n] = __builtin_amdgcn_mfma_f32_16x16x32_bf16(af[m], bk[n], acc[m][n], 0, 0, 0);
        __builtin_amdgcn_s_setprio(0);

        rdB(Bb, 1, bk); rdA(Ab, 1, af);
        stageA(b2, 2, st); stageA(b2, 3, st);
        stageB(b2, 0, st); stageB(b2, 1, st);
        LGKM0();
        __builtin_amdgcn_s_setprio(1);
        #pragma unroll
        for (int m = 0; m < 4; ++m)
            #pragma unroll
            for (int n = 0; n < 4; ++n)
                acc[m][n] = __builtin_amdgcn_mfma_f32_16x16x32_bf16(af[m], bk[n], acc[m][n], 0, 0, 0);
        __builtin_amdgcn_s_setprio(0);

        VMCNT(6);
        BARRIER();
    }

    #pragma unroll
    for (int m = 0; m < 4; ++m) {
        int r0 = bm + wr * 64 + m * 16 + lhi * 4;
        #pragma unroll
        for (int n = 0; n < 4; ++n) {
            int c = bn + wc * 64 + n * 16 + l15;
            #pragma unroll
            for (int j = 0; j < 4; ++j)
                C[(size_t)(r0 + j) * N + c] = acc[m][n][j];
        }
    }
}

// ---------------------------------------------------------------- fallback GEMM (round-1)
#define BM 128
#define BN 128
#define BK 32
#define LDSK 40

template<bool OUT_BF16>
__global__ __launch_bounds__(256) void gemm_aBf16(
    const bf16* __restrict__ A,
    const float* __restrict__ B0, const float* __restrict__ B1,
    void* __restrict__ C0, void* __restrict__ C1,
    int M, int N, int K)
{
    __shared__ alignas(16) bf16 Al[BM][LDSK];
    __shared__ alignas(16) bf16 Bt[BN][LDSK];

    const float* __restrict__ B = blockIdx.z ? B1 : B0;
    void* __restrict__ C = blockIdx.z ? C1 : C0;

    const int tid  = threadIdx.x;
    const int lane = tid & 63;
    const int wave = tid >> 6;
    const int wm = (wave >> 1) * 64;
    const int wn = (wave & 1) * 64;
    const int bm = blockIdx.y * BM;
    const int bn = blockIdx.x * BN;
    const int l15 = lane & 15;
    const int lhi = lane >> 4;

    f32x4 acc[4][4] = {};

    for (int k0 = 0; k0 < K; k0 += BK) {
        #pragma unroll
        for (int it = 0; it < 2; ++it) {
            int idx = it * 256 + tid;
            int row = idx >> 2;
            int ko  = idx & 3;
            bf16x8 v = *reinterpret_cast<const bf16x8*>(
                A + (size_t)(bm + row) * K + k0 + ko * 8);
            *reinterpret_cast<bf16x8*>(&Al[row][ko * 8]) = v;
        }
        {
            int n = tid & 127;
            int kbase = (tid >> 7) * 8;
            const float* bp = B + (size_t)k0 * N + bn + n;
            #pragma unroll
            for (int half = 0; half < 2; ++half) {
                bf16x8 v;
                #pragma unroll
                for (int j = 0; j < 8; ++j)
                    v[j] = (bf16)bp[(size_t)(half * 16 + kbase + j) * N];
                *reinterpret_cast<bf16x8*>(&Bt[n][half * 16 + kbase]) = v;
            }
        }
        __syncthreads();

        bf16x8 af[4], bfv[4];
        #pragma unroll
        for (int m = 0; m < 4; ++m)
            af[m] = *reinterpret_cast<const bf16x8*>(&Al[wm + m * 16 + l15][lhi * 8]);
        #pragma unroll
        for (int n = 0; n < 4; ++n)
            bfv[n] = *reinterpret_cast<const bf16x8*>(&Bt[wn + n * 16 + l15][lhi * 8]);
        #pragma unroll
        for (int m = 0; m < 4; ++m)
            #pragma unroll
            for (int n = 0; n < 4; ++n)
                acc[m][n] = __builtin_amdgcn_mfma_f32_16x16x32_bf16(
                    af[m], bfv[n], acc[m][n], 0, 0, 0);
        __syncthreads();
    }

    #pragma unroll
    for (int m = 0; m < 4; ++m) {
        int r0 = bm + wm + m * 16 + lhi * 4;
        #pragma unroll
        for (int n = 0; n < 4; ++n) {
            int c = bn + wn + n * 16 + l15;
            #pragma unroll
            for (int j = 0; j < 4; ++j) {
                if constexpr (OUT_BF16)
                    reinterpret_cast<bf16*>(C)[(size_t)(r0 + j) * N + c] = (bf16)acc[m][n][j];
                else
                    reinterpret_cast<float*>(C)[(size_t)(r0 + j) * N + c] = acc[m][n][j];
            }
        }
    }
}

// ---------------------------------------------------------------- flash attention v5 (exp2 softmax)
#define QBLK 128
#define KVBLK 64
#define NQT (S/QBLK)

template<bool MASK>
__device__ __forceinline__ void attn_tile(
    int t0, int q0, int wave, int l15, int lhi,
    const bf16x8* qf, const char* Kl, const char* Vl, char* Plw,
    f32x4* o, float* m_i, float* l_i)
{
    f32x4 sc[4] = {};
    __builtin_amdgcn_s_setprio(1);
    #pragma unroll
    for (int n = 0; n < 4; ++n) {
        int row = n * 16 + l15;
        #pragma unroll
        for (int kk = 0; kk < 4; ++kk) {
            bf16x8 kf = *reinterpret_cast<const bf16x8*>(
                Kl + row * 256 + ((((kk * 4 + lhi)) ^ (l15 & 7)) << 4));
            sc[n] = __builtin_amdgcn_mfma_f32_16x16x32_bf16(qf[kk], kf, sc[n], 0, 0, 0);
        }
    }
    __builtin_amdgcn_s_setprio(0);

    float corr[4];
    #pragma unroll
    for (int j = 0; j < 4; ++j) {
        const int qr = q0 + wave * 16 + lhi * 4 + j;
        float vals[4];
        float mx = -1e30f;
        #pragma unroll
        for (int n = 0; n < 4; ++n) {
            float v = sc[n][j];
            if constexpr (MASK) {
                int t = t0 + n * 16 + l15;
                if (t > qr) v = -1e30f;
            }
            vals[n] = v;
            mx = fmaxf(mx, v);
        }
        #pragma unroll
        for (int ms = 1; ms < 16; ms <<= 1)
            mx = fmaxf(mx, __shfl_xor(mx, ms, 16));
        float mnew, cr;
        if (mx <= m_i[j] + 8.0f) { mnew = m_i[j]; cr = 1.0f; }
        else                     { mnew = mx; cr = exp2f(m_i[j] - mnew); }
        float rsum = 0.f;
        #pragma unroll
        for (int n = 0; n < 4; ++n) {
            float p = exp2f(vals[n] - mnew);
            rsum += p;
            int r = lhi * 4 + j;
            int off = ((r << 7) + ((n * 16 + l15) << 1)) ^ ((r & 7) << 4);
            *reinterpret_cast<bf16*>(Plw + off) = (bf16)p;
        }
        #pragma unroll
        for (int ms = 1; ms < 16; ms <<= 1)
            rsum += __shfl_xor(rsum, ms, 16);
        l_i[j] = l_i[j] * cr + rsum;
        m_i[j] = mnew;
        corr[j] = cr;
    }

    if ((corr[0] != 1.f) | (corr[1] != 1.f) | (corr[2] != 1.f) | (corr[3] != 1.f)) {
        #pragma unroll
        for (int n = 0; n < 8; ++n)
            #pragma unroll
            for (int j = 0; j < 4; ++j)
                o[n][j] *= corr[j];
    }

    __builtin_amdgcn_s_setprio(1);
    #pragma unroll
    for (int kk = 0; kk < 2; ++kk) {
        bf16x8 pf = *reinterpret_cast<const bf16x8*>(
            Plw + (l15 << 7) + ((((kk * 4 + lhi)) ^ (l15 & 7)) << 4));
        #pragma unroll
        for (int n = 0; n < 8; ++n) {
            int d = n * 16 + l15;
            bf16x8 vf = *reinterpret_cast<const bf16x8*>(
                Vl + (d << 7) + ((((kk * 4 + lhi)) ^ (d & 7)) << 4));
            o[n] = __builtin_amdgcn_mfma_f32_16x16x32_bf16(pf, vf, o[n], 0, 0, 0);
        }
    }
    __builtin_amdgcn_s_setprio(0);
}

__global__ __launch_bounds__(512) void flash_fwd5(
    const bf16* __restrict__ Q, const bf16* __restrict__ Kr,
    const bf16* __restrict__ VtG, bf16* __restrict__ ctx)
{
    extern __shared__ char fsm[];   // buf b: K @ b*32768, V @ +16384; P @ 65536 (8x2KB)

    const int tid  = threadIdx.x;
    const int lane = tid & 63;
    const int wave = tid >> 6;
    const int l15 = lane & 15;
    const int lhi = lane >> 4;
    const int bid = blockIdx.x;
    const int qt = (NQT - 1) - (bid >> 5);
    const int h  = ((bid & 7) << 2) | ((bid >> 3) & 3);
    const int g  = h >> 2;
    const int q0 = qt * QBLK;
    char* Plw = fsm + 65536 + wave * 2048;

    bf16x8 qf[4];
    {
        const bf16* qp = Q + (size_t)(q0 + wave * 16 + l15) * HD + h * DH + lhi * 8;
        #pragma unroll
        for (int kk = 0; kk < 4; ++kk)
            qf[kk] = *reinterpret_cast<const bf16x8*>(qp + kk * 32);
    }

    f32x4 o[8] = {};
    float m_i[4] = { -1e30f, -1e30f, -1e30f, -1e30f };
    float l_i[4] = {};

    auto stage = [&](int t0, int buf) {
        char* Kl = fsm + buf * 32768;
        char* Vl = Kl + 16384;
        #pragma unroll
        for (int t = 0; t < 2; ++t) {
            int ch = t * 512 + tid;
            {
                int row = ch >> 4, ci = ch & 15;
                gload16(Kr + (size_t)(t0 + row) * GD + g * DH + ((ci ^ (row & 7)) << 3),
                        Kl + ch * 16);
            }
            {
                int d = ch >> 3, ci = ch & 7;
                gload16(VtG + (size_t)(g * DH + d) * S + t0 + ((ci ^ (d & 7)) << 3),
                        Vl + ch * 16);
            }
        }
    };

    const int nt = 2 * qt + 2;
    stage(0, 0);
    VMCNT(0);
    BARRIER();

    for (int it = 0; it < nt; ++it) {
        if (it + 1 < nt) stage((it + 1) * KVBLK, (it + 1) & 1);
        const char* Kl = fsm + (it & 1) * 32768;
        const char* Vl = Kl + 16384;
        if (it >= nt - 2)
            attn_tile<true>(it * KVBLK, q0, wave, l15, lhi, qf, Kl, Vl, Plw, o, m_i, l_i);
        else
            attn_tile<false>(it * KVBLK, q0, wave, l15, lhi, qf, Kl, Vl, Plw, o, m_i, l_i);
        VMCNT(0);
        BARRIER();
    }

    #pragma unroll
    for (int n = 0; n < 8; ++n) {
        int c = h * DH + n * 16 + l15;
        #pragma unroll
        for (int j = 0; j < 4; ++j) {
            int r = q0 + wave * 16 + lhi * 4 + j;
            ctx[(size_t)r * HD + c] = (bf16)(o[n][j] / l_i[j]);
        }
    }
}

// ---------------------------------------------------------------- launch
extern "C" void kernel_launch(void* const* d_in, const int* in_sizes, int n_in,
                              void* d_out, int out_size, void* d_ws, size_t ws_size,
                              hipStream_t stream)
{
    const float* x    = (const float*)d_in[0];
    const float* cosT = (const float*)d_in[2];
    const float* sinT = (const float*)d_in[3];
    const float* Wq   = (const float*)d_in[4];
    const float* Wk   = (const float*)d_in[5];
    const float* Wv   = (const float*)d_in[6];
    const float* Wo   = (const float*)d_in[7];
    float* out = (float*)d_out;

    const size_t MB = (size_t)1 << 20;
    char* ws = (char*)d_ws;
    bf16* xb  = (bf16*)ws;                         // 16MB
    bf16* ctx = (bf16*)(ws + 16 * MB);             // 16MB
    bf16* Qb  = (bf16*)d_out;                      // d_out scratch (dead until final GEMM)
    bf16* Kb  = Qb + (size_t)S * HD;
    bf16* Vb  = Kb + (size_t)S * GD;
    bf16* VtG = Vb + (size_t)S * GD;

    const bool fast = ws_size >= 112 * MB;
    const float qscale = 0.08838834764831845f * 1.4426950408889634f;

    hipFuncSetAttribute(reinterpret_cast<const void*>(&flash_fwd5),
                        hipFuncAttributeMaxDynamicSharedMemorySize, 81920);

    if (fast) {
        bf16* Wqkvt = (bf16*)(ws + 32 * MB);       // [6144][4096] bf16 = 48MB
        bf16* Wot   = (bf16*)(ws + 80 * MB);       // [4096][4096] bf16 = 32MB

        hipFuncSetAttribute(reinterpret_cast<const void*>(&gemm8p),
                            hipFuncAttributeMaxDynamicSharedMemorySize, 131072);
        hipFuncSetAttribute(reinterpret_cast<const void*>(&gemm3b),
                            hipFuncAttributeMaxDynamicSharedMemorySize, 147456);

        prep_fused<<<2048, 256, 0, stream>>>(x, xb, Wq, Wk, Wv, Wqkvt);

        gemm8p<<<256, 512, 131072, stream>>>(
            xb, Wqkvt, Qb, Kb, Vb, Wo, Wot, HD + 2 * GD, D, 192);

        rope_vt_fused<<<20608, 256, 0, stream>>>(Qb, Kb, Vb, VtG, cosT, sinT, qscale);

        flash_fwd5<<<NQT * H, 512, 81920, stream>>>(Qb, Kb, VtG, ctx);

        gemm3b<<<256, 512, 147456, stream>>>(ctx, Wot, out, D, HD);
    } else {
        cast_f32_bf16<<<(S * D / 4 + 255) / 256, 256, 0, stream>>>(x, xb, S * D / 4);

        gemm_aBf16<true><<<dim3(HD / BN, S / BM, 1), 256, 0, stream>>>(
            xb, Wq, Wq, (void*)Qb, (void*)Qb, S, HD, D);
        gemm_aBf16<true><<<dim3(GD / BN, S / BM, 2), 256, 0, stream>>>(
            xb, Wk, Wv, (void*)Kb, (void*)Vb, S, GD, D);

        rope_inplace<<<(S * HD / 2 + 255) / 256, 256, 0, stream>>>(Qb, cosT, sinT, HD, S * HD / 2, qscale);
        rope_inplace<<<(S * GD / 2 + 255) / 256, 256, 0, stream>>>(Kb, cosT, sinT, GD, S * GD / 2, 1.0f);

        transpose_to_bf16<false><<<dim3(GD / 256, S / 64), 256, 0, stream>>>(Vb, VtG, S, GD);

        flash_fwd5<<<NQT * H, 512, 81920, stream>>>(Qb, Kb, VtG, ctx);

        gemm_aBf16<false><<<dim3(D / BN, S / BM, 1), 256, 0, stream>>>(
            ctx, Wo, Wo, (void*)out, (void*)out, S, D, HD);
    }

    (void)in_sizes; (void)n_in; (void)out_size; (void)ws_size;
}

// Round 11
// 319.008 us; speedup vs baseline: 1.2958x; 1.0540x over previous
//
#include <hip/hip_runtime.h>
#include <hip/hip_bf16.h>
#include <cstdint>
#include <cstddef>

#define S 2048
#define D 4096
#define H 32
#define G 8
#define DH 128
#define HD (H*DH)   // 4096
#define GD (G*DH)   // 1024

typedef __bf16 bf16;
typedef __bf16 bf16x4 __attribute__((ext_vector_type(4)));
typedef __bf16 bf16x8 __attribute__((ext_vector_type(8)));
typedef float f32x4 __attribute__((ext_vector_type(4)));

__device__ __forceinline__ void gload16(const void* g, void* l) {
    __builtin_amdgcn_global_load_lds(
        (const __attribute__((address_space(1))) void*)g,
        (__attribute__((address_space(3))) void*)l, 16, 0, 0);
}

#define FENCE() asm volatile("" ::: "memory")
#define BARRIER() do { FENCE(); __builtin_amdgcn_s_barrier(); FENCE(); } while (0)
#define VMCNT(n)  asm volatile("s_waitcnt vmcnt(" #n ")" ::: "memory")
#define LGKM0()   do { asm volatile("s_waitcnt lgkmcnt(0)" ::: "memory"); \
                       __builtin_amdgcn_sched_barrier(0); } while (0)

// ---------------------------------------------------------------- fused prep:
// blocks [0,512): cast x f32->bf16 ; [512,1536): Wq^T ; [1536,1792): Wk^T ; [1792,2048): Wv^T
__global__ __launch_bounds__(256) void prep_fused(
    const float* __restrict__ x, bf16* __restrict__ xb,
    const float* __restrict__ Wq, const float* __restrict__ Wk,
    const float* __restrict__ Wv, bf16* __restrict__ Wqkvt)
{
    const int b = blockIdx.x, tid = threadIdx.x;
    if (b < 512) {
        int i = b * 4096 + tid;
        #pragma unroll
        for (int it = 0; it < 16; ++it, i += 256) {
            float4 v = reinterpret_cast<const float4*>(x)[i];
            bf16x4 o = { (bf16)v.x, (bf16)v.y, (bf16)v.z, (bf16)v.w };
            reinterpret_cast<bf16x4*>(xb)[i] = o;
        }
        return;
    }
    const float* in; bf16* out; int Cc, bx, by;
    if (b < 1536)      { int tb = b - 512;  in = Wq; out = Wqkvt;                       Cc = HD; bx = tb & 15; by = tb >> 4; }
    else if (b < 1792) { int tb = b - 1536; in = Wk; out = Wqkvt + (size_t)HD * D;      Cc = GD; bx = tb & 3;  by = tb >> 2; }
    else               { int tb = b - 1792; in = Wv; out = Wqkvt + (size_t)(HD+GD) * D; Cc = GD; bx = tb & 3;  by = tb >> 2; }
    const int r0 = by * 64 + (tid & 7) * 8;
    const int c0 = bx * 256 + (tid >> 3) * 8;
    bf16 m[8][8];
    #pragma unroll
    for (int j = 0; j < 8; ++j) {
        const float* p = in + (size_t)(r0 + j) * Cc + c0;
        float4 a = *reinterpret_cast<const float4*>(p);
        float4 bq = *reinterpret_cast<const float4*>(p + 4);
        m[j][0] = (bf16)a.x;  m[j][1] = (bf16)a.y;  m[j][2] = (bf16)a.z;  m[j][3] = (bf16)a.w;
        m[j][4] = (bf16)bq.x; m[j][5] = (bf16)bq.y; m[j][6] = (bf16)bq.z; m[j][7] = (bf16)bq.w;
    }
    #pragma unroll
    for (int i = 0; i < 8; ++i) {
        bf16x8 ov;
        #pragma unroll
        for (int j = 0; j < 8; ++j) ov[j] = m[j][i];
        *reinterpret_cast<bf16x8*>(out + (size_t)(c0 + i) * D + r0) = ov;
    }
}

// ---------------------------------------------------------------- fused rope + V^T
__global__ __launch_bounds__(256) void rope_vt_fused(
    bf16* __restrict__ Qb, bf16* __restrict__ Kb,
    const bf16* __restrict__ Vb, bf16* __restrict__ VtG,
    const float* __restrict__ cosT, const float* __restrict__ sinT, float qs)
{
    const int b = blockIdx.x, tid = threadIdx.x;
    if (b < 20480) {
        bf16* Y; int ncols, idx; float scale;
        if (b < 16384) { Y = Qb; ncols = HD; idx = b * 256 + tid;           scale = qs; }
        else           { Y = Kb; ncols = GD; idx = (b - 16384) * 256 + tid; scale = 1.0f; }
        int pairs = ncols >> 1;
        int s = idx / pairs;
        int p = idx - s * pairs;
        int head = p >> 6;
        int d = p & 63;
        size_t base = (size_t)s * ncols + head * DH;
        float c  = cosT[s * DH + d];
        float sn = sinT[s * DH + d];
        float a = (float)Y[base + d];
        float bb = (float)Y[base + d + 64];
        Y[base + d]      = (bf16)((a * c - bb * sn) * scale);
        Y[base + d + 64] = (bf16)((bb * c + a * sn) * scale);
        return;
    }
    const int tb = b - 20480;
    const int r0 = (tb >> 2) * 64 + (tid & 7) * 8;
    const int c0 = (tb & 3) * 256 + (tid >> 3) * 8;
    bf16 m[8][8];
    #pragma unroll
    for (int j = 0; j < 8; ++j) {
        bf16x8 v = *reinterpret_cast<const bf16x8*>(Vb + (size_t)(r0 + j) * GD + c0);
        #pragma unroll
        for (int i = 0; i < 8; ++i) m[j][i] = v[i];
    }
    #pragma unroll
    for (int i = 0; i < 8; ++i) {
        bf16x8 ov;
        #pragma unroll
        for (int j = 0; j < 8; ++j) ov[j] = m[j][i];
        *reinterpret_cast<bf16x8*>(VtG + (size_t)(c0 + i) * S + r0) = ov;
    }
}

// ---------------------------------------------------------------- standalone kernels (fallback path)
__global__ __launch_bounds__(256) void cast_f32_bf16(const float* __restrict__ in,
                                                     bf16* __restrict__ out, int n4)
{
    int i = blockIdx.x * 256 + threadIdx.x;
    if (i < n4) {
        float4 v = reinterpret_cast<const float4*>(in)[i];
        bf16x4 o = { (bf16)v.x, (bf16)v.y, (bf16)v.z, (bf16)v.w };
        reinterpret_cast<bf16x4*>(out)[i] = o;
    }
}

template<bool IN_F32>
__global__ __launch_bounds__(256) void transpose_to_bf16(
    const void* __restrict__ in, bf16* __restrict__ out, int R, int C)
{
    const int r0 = blockIdx.y * 64 + (threadIdx.x & 7) * 8;
    const int c0 = blockIdx.x * 256 + (threadIdx.x >> 3) * 8;
    bf16 m[8][8];
    #pragma unroll
    for (int j = 0; j < 8; ++j) {
        if constexpr (IN_F32) {
            const float* p = (const float*)in + (size_t)(r0 + j) * C + c0;
            float4 a = *reinterpret_cast<const float4*>(p);
            float4 b = *reinterpret_cast<const float4*>(p + 4);
            m[j][0] = (bf16)a.x; m[j][1] = (bf16)a.y; m[j][2] = (bf16)a.z; m[j][3] = (bf16)a.w;
            m[j][4] = (bf16)b.x; m[j][5] = (bf16)b.y; m[j][6] = (bf16)b.z; m[j][7] = (bf16)b.w;
        } else {
            const bf16* p = (const bf16*)in + (size_t)(r0 + j) * C + c0;
            bf16x8 v = *reinterpret_cast<const bf16x8*>(p);
            #pragma unroll
            for (int i = 0; i < 8; ++i) m[j][i] = v[i];
        }
    }
    #pragma unroll
    for (int i = 0; i < 8; ++i) {
        bf16x8 ov;
        #pragma unroll
        for (int j = 0; j < 8; ++j) ov[j] = m[j][i];
        *reinterpret_cast<bf16x8*>(out + (size_t)(c0 + i) * R + r0) = ov;
    }
}

__global__ __launch_bounds__(256) void rope_inplace(bf16* __restrict__ Y,
                                                    const float* __restrict__ cosT,
                                                    const float* __restrict__ sinT,
                                                    int ncols, int total, float scale)
{
    int idx = blockIdx.x * 256 + threadIdx.x;
    if (idx >= total) return;
    int pairs = ncols >> 1;
    int s = idx / pairs;
    int p = idx - s * pairs;
    int head = p >> 6;
    int d = p & 63;
    size_t base = (size_t)s * ncols + head * DH;
    float c  = cosT[s * DH + d];
    float sn = sinT[s * DH + d];
    float a = (float)Y[base + d];
    float b = (float)Y[base + d + 64];
    Y[base + d]      = (bf16)((a * c - b * sn) * scale);
    Y[base + d + 64] = (bf16)((b * c + a * sn) * scale);
}

// ================================================================ QKV GEMM (r4 8-phase 256x256)
// Blocks [0,192): grid 8(M) x 24(N), 2D XCD regions (4x6 per XCD).
// Blocks [192,256): fused Wo transpose.
__global__ __launch_bounds__(512) void gemm8p(
    const bf16* __restrict__ A, const bf16* __restrict__ Bt,
    bf16* __restrict__ Qout, bf16* __restrict__ Kout, bf16* __restrict__ Vout,
    const float* __restrict__ WoIn, bf16* __restrict__ WotOut,
    int N, int K, int ngemm)
{
    extern __shared__ char smem[];   // buf d: A @ d*65536, B @ d*65536+32768
    const int tid = threadIdx.x;

    if ((int)blockIdx.x >= ngemm) {
        const int tb = blockIdx.x - ngemm;               // 0..63
        const int r0 = tb * 64 + (tid & 7) * 8;
        #pragma unroll 1
        for (int pass = 0; pass < 8; ++pass) {
            const int c0 = pass * 512 + (tid >> 3) * 8;
            bf16 m[8][8];
            #pragma unroll
            for (int j = 0; j < 8; ++j) {
                const float* p = WoIn + (size_t)(r0 + j) * D + c0;
                float4 a = *reinterpret_cast<const float4*>(p);
                float4 b = *reinterpret_cast<const float4*>(p + 4);
                m[j][0] = (bf16)a.x; m[j][1] = (bf16)a.y; m[j][2] = (bf16)a.z; m[j][3] = (bf16)a.w;
                m[j][4] = (bf16)b.x; m[j][5] = (bf16)b.y; m[j][6] = (bf16)b.z; m[j][7] = (bf16)b.w;
            }
            #pragma unroll
            for (int i = 0; i < 8; ++i) {
                bf16x8 ov;
                #pragma unroll
                for (int j = 0; j < 8; ++j) ov[j] = m[j][i];
                *reinterpret_cast<bf16x8*>(WotOut + (size_t)(c0 + i) * HD + r0) = ov;
            }
        }
        return;
    }

    const int lane = tid & 63, wave = tid >> 6;
    const int wr = wave >> 2, wc = wave & 3;
    const int l15 = lane & 15, lhi = lane >> 4;
    const int r8 = lane >> 3, c8 = lane & 7;
    const int csw = ((c8 ^ r8) << 3);

    const int x = blockIdx.x & 7, i = blockIdx.x >> 3;
    const int brow = (x >> 2) * 4 + (i & 3);
    const int bcol = (x & 3) * 6 + (i >> 2);
    const int bm = brow * 256, bn = bcol * 256;
    const int NT = K >> 6;

    auto stageA = [&](int buf, int h, int t) {
        #pragma unroll
        for (int L = 0; L < 2; ++L) {
            int row0 = L * 128 + h * 64 + wave * 8;
            gload16(A + (size_t)(bm + row0 + r8) * K + (t << 6) + csw,
                    smem + buf * 65536 + row0 * 128);
        }
    };
    auto stageB = [&](int buf, int h, int t) {
        #pragma unroll
        for (int L = 0; L < 2; ++L) {
            int row0 = h * 128 + L * 64 + wave * 8;
            gload16(Bt + (size_t)(bn + row0 + r8) * K + (t << 6) + csw,
                    smem + buf * 65536 + 32768 + row0 * 128);
        }
    };
    auto rdA = [&](const char* Ab, int mh, int ks, bf16x8* af) {
        #pragma unroll
        for (int m = 0; m < 4; ++m) {
            int row = wr * 128 + mh * 64 + m * 16 + l15;
            int ch = (ks * 4 + lhi) ^ (l15 & 7);
            af[m] = *reinterpret_cast<const bf16x8*>(Ab + row * 128 + ch * 16);
        }
    };
    auto rdB = [&](const char* Bb, int ks, bf16x8* bfv) {
        #pragma unroll
        for (int n = 0; n < 4; ++n) {
            int row = wc * 64 + n * 16 + l15;
            int ch = (ks * 4 + lhi) ^ (l15 & 7);
            bfv[n] = *reinterpret_cast<const bf16x8*>(Bb + row * 128 + ch * 16);
        }
    };

    f32x4 acc[8][4] = {};

    auto mm = [&](int mh, const bf16x8* af, const bf16x8* bfv) {
        LGKM0();
        __builtin_amdgcn_s_setprio(1);
        #pragma unroll
        for (int m = 0; m < 4; ++m)
            #pragma unroll
            for (int n = 0; n < 4; ++n)
                acc[mh * 4 + m][n] = __builtin_amdgcn_mfma_f32_16x16x32_bf16(
                    af[m], bfv[n], acc[mh * 4 + m][n], 0, 0, 0);
        __builtin_amdgcn_s_setprio(0);
    };

    stageA(0, 0, 0); stageA(0, 1, 0); stageB(0, 0, 0); stageB(0, 1, 0);
    stageA(1, 0, 1);
    VMCNT(2);
    BARRIER();

    const char* A0 = smem;
    const char* B0 = smem + 32768;
    const char* A1 = smem + 65536;
    const char* B1 = smem + 65536 + 32768;

    for (int j = 0; j < (NT >> 1); ++j) {
        const int tb = 2 * j + 1;
        const int t2 = (2 * j + 2 < NT) ? 2 * j + 2 : NT - 1;
        const int t3 = (2 * j + 3 < NT) ? 2 * j + 3 : NT - 1;
        bf16x8 af[4], bk0[4], bk1[4];

        // ---- tile a (buf0)
        rdB(B0, 0, bk0); rdA(A0, 0, 0, af);
        stageA(1, 1, tb);
        mm(0, af, bk0);
        BARRIER();

        rdB(B0, 1, bk1); rdA(A0, 0, 1, af);
        stageB(1, 0, tb);
        mm(0, af, bk1);
        BARRIER();

        rdA(A0, 1, 0, af);
        stageB(1, 1, tb);
        mm(1, af, bk0);
        BARRIER();

        rdA(A0, 1, 1, af);
        stageA(0, 0, t2);
        mm(1, af, bk1);
        VMCNT(2);
        BARRIER();

        // ---- tile b (buf1)
        rdB(B1, 0, bk0); rdA(A1, 0, 0, af);
        stageA(0, 1, t2);
        mm(0, af, bk0);
        BARRIER();

        rdB(B1, 1, bk1); rdA(A1, 0, 1, af);
        stageB(0, 0, t2);
        mm(0, af, bk1);
        BARRIER();

        rdA(A1, 1, 0, af);
        stageB(0, 1, t2);
        mm(1, af, bk0);
        BARRIER();

        rdA(A1, 1, 1, af);
        stageA(1, 0, t3);
        mm(1, af, bk1);
        VMCNT(2);
        BARRIER();
    }

    #pragma unroll
    for (int m = 0; m < 8; ++m) {
        int r0 = bm + wr * 128 + m * 16 + lhi * 4;
        #pragma unroll
        for (int n = 0; n < 4; ++n) {
            int c = bn + wc * 64 + n * 16 + l15;
            #pragma unroll
            for (int j = 0; j < 4; ++j) {
                bf16 v = (bf16)acc[m][n][j];
                if (bn < HD)
                    Qout[(size_t)(r0 + j) * HD + c] = v;
                else if (bn < HD + GD)
                    Kout[(size_t)(r0 + j) * GD + (c - HD)] = v;
                else
                    Vout[(size_t)(r0 + j) * GD + (c - HD - GD)] = v;
            }
        }
    }
}

// ================================================================ Wo GEMM: 256x128, 3-buf, 2D XCD regions
__global__ __launch_bounds__(512, 2) void gemm3b(
    const bf16* __restrict__ A, const bf16* __restrict__ Bt,
    float* __restrict__ C, int N, int K)
{
    extern __shared__ char smem[];   // buf b @ b*49152: A 32KB, B @ +32768 (16KB)
    const int tid = threadIdx.x, lane = tid & 63, wave = tid >> 6;
    const int wr = wave >> 1, wc = wave & 1;
    const int l15 = lane & 15, lhi = lane >> 4;
    const int r8 = lane >> 3, c8 = lane & 7;
    const int csw = ((c8 ^ r8) << 3);

    const int x = blockIdx.x & 7, i = blockIdx.x >> 3;
    const int brow = (x >> 2) * 4 + (i & 3);
    const int bcol = (x & 3) * 8 + (i >> 2);
    const int bm = brow * 256, bn = bcol * 128;
    const int NT = K >> 6;

    auto stageA = [&](int buf, int L, int t) {
        int row0 = L * 64 + wave * 8;
        gload16(A + (size_t)(bm + row0 + r8) * K + (t << 6) + csw,
                smem + buf * 49152 + row0 * 128);
    };
    auto stageB = [&](int buf, int L, int t) {
        int row0 = L * 64 + wave * 8;
        gload16(Bt + (size_t)(bn + row0 + r8) * K + (t << 6) + csw,
                smem + buf * 49152 + 32768 + row0 * 128);
    };
    auto rdA = [&](const char* Ab, int ks, bf16x8* af) {
        #pragma unroll
        for (int m = 0; m < 4; ++m) {
            int row = wr * 64 + m * 16 + l15;
            int ch = (ks * 4 + lhi) ^ (l15 & 7);
            af[m] = *reinterpret_cast<const bf16x8*>(Ab + row * 128 + ch * 16);
        }
    };
    auto rdB = [&](const char* Bb, int ks, bf16x8* bfv) {
        #pragma unroll
        for (int n = 0; n < 4; ++n) {
            int row = wc * 64 + n * 16 + l15;
            int ch = (ks * 4 + lhi) ^ (l15 & 7);
            bfv[n] = *reinterpret_cast<const bf16x8*>(Bb + row * 128 + ch * 16);
        }
    };

    f32x4 acc[4][4] = {};

    #pragma unroll
    for (int L = 0; L < 4; ++L) stageA(0, L, 0);
    stageB(0, 0, 0); stageB(0, 1, 0);
    #pragma unroll
    for (int L = 0; L < 4; ++L) stageA(1, L, (1 < NT) ? 1 : 0);
    stageB(1, 0, (1 < NT) ? 1 : 0); stageB(1, 1, (1 < NT) ? 1 : 0);
    VMCNT(6);
    BARRIER();

    for (int t = 0; t < NT; ++t) {
        const char* Ab = smem + (t % 3) * 49152;
        const char* Bb = Ab + 32768;
        const int b2 = (t + 2) % 3;
        const int st = (t + 2 < NT) ? t + 2 : NT - 1;
        bf16x8 af[4], bk[4];

        rdB(Bb, 0, bk); rdA(Ab, 0, af);
        stageA(b2, 0, st); stageA(b2, 1, st);
        LGKM0();
        __builtin_amdgcn_s_setprio(1);
        #pragma unroll
        for (int m = 0; m < 4; ++m)
            #pragma unroll
            for (int n = 0; n < 4; ++n)
                acc[m][n] = __builtin_amdgcn_mfma_f32_16x16x32_bf16(af[m], bk[n], acc[m][n], 0, 0, 0);
        __builtin_amdgcn_s_setprio(0);

        rdB(Bb, 1, bk); rdA(Ab, 1, af);
        stageA(b2, 2, st); stageA(b2, 3, st);
        stageB(b2, 0, st); stageB(b2, 1, st);
        LGKM0();
        __builtin_amdgcn_s_setprio(1);
        #pragma unroll
        for (int m = 0; m < 4; ++m)
            #pragma unroll
            for (int n = 0; n < 4; ++n)
                acc[m][n] = __builtin_amdgcn_mfma_f32_16x16x32_bf16(af[m], bk[n], acc[m][n], 0, 0, 0);
        __builtin_amdgcn_s_setprio(0);

        VMCNT(6);
        BARRIER();
    }

    #pragma unroll
    for (int m = 0; m < 4; ++m) {
        int r0 = bm + wr * 64 + m * 16 + lhi * 4;
        #pragma unroll
        for (int n = 0; n < 4; ++n) {
            int c = bn + wc * 64 + n * 16 + l15;
            #pragma unroll
            for (int j = 0; j < 4; ++j)
                C[(size_t)(r0 + j) * N + c] = acc[m][n][j];
        }
    }
}

// ---------------------------------------------------------------- fallback GEMM (round-1)
#define BM 128
#define BN 128
#define BK 32
#define LDSK 40

template<bool OUT_BF16>
__global__ __launch_bounds__(256) void gemm_aBf16(
    const bf16* __restrict__ A,
    const float* __restrict__ B0, const float* __restrict__ B1,
    void* __restrict__ C0, void* __restrict__ C1,
    int M, int N, int K)
{
    __shared__ alignas(16) bf16 Al[BM][LDSK];
    __shared__ alignas(16) bf16 Bt[BN][LDSK];

    const float* __restrict__ B = blockIdx.z ? B1 : B0;
    void* __restrict__ C = blockIdx.z ? C1 : C0;

    const int tid  = threadIdx.x;
    const int lane = tid & 63;
    const int wave = tid >> 6;
    const int wm = (wave >> 1) * 64;
    const int wn = (wave & 1) * 64;
    const int bm = blockIdx.y * BM;
    const int bn = blockIdx.x * BN;
    const int l15 = lane & 15;
    const int lhi = lane >> 4;

    f32x4 acc[4][4] = {};

    for (int k0 = 0; k0 < K; k0 += BK) {
        #pragma unroll
        for (int it = 0; it < 2; ++it) {
            int idx = it * 256 + tid;
            int row = idx >> 2;
            int ko  = idx & 3;
            bf16x8 v = *reinterpret_cast<const bf16x8*>(
                A + (size_t)(bm + row) * K + k0 + ko * 8);
            *reinterpret_cast<bf16x8*>(&Al[row][ko * 8]) = v;
        }
        {
            int n = tid & 127;
            int kbase = (tid >> 7) * 8;
            const float* bp = B + (size_t)k0 * N + bn + n;
            #pragma unroll
            for (int half = 0; half < 2; ++half) {
                bf16x8 v;
                #pragma unroll
                for (int j = 0; j < 8; ++j)
                    v[j] = (bf16)bp[(size_t)(half * 16 + kbase + j) * N];
                *reinterpret_cast<bf16x8*>(&Bt[n][half * 16 + kbase]) = v;
            }
        }
        __syncthreads();

        bf16x8 af[4], bfv[4];
        #pragma unroll
        for (int m = 0; m < 4; ++m)
            af[m] = *reinterpret_cast<const bf16x8*>(&Al[wm + m * 16 + l15][lhi * 8]);
        #pragma unroll
        for (int n = 0; n < 4; ++n)
            bfv[n] = *reinterpret_cast<const bf16x8*>(&Bt[wn + n * 16 + l15][lhi * 8]);
        #pragma unroll
        for (int m = 0; m < 4; ++m)
            #pragma unroll
            for (int n = 0; n < 4; ++n)
                acc[m][n] = __builtin_amdgcn_mfma_f32_16x16x32_bf16(
                    af[m], bfv[n], acc[m][n], 0, 0, 0);
        __syncthreads();
    }

    #pragma unroll
    for (int m = 0; m < 4; ++m) {
        int r0 = bm + wm + m * 16 + lhi * 4;
        #pragma unroll
        for (int n = 0; n < 4; ++n) {
            int c = bn + wn + n * 16 + l15;
            #pragma unroll
            for (int j = 0; j < 4; ++j) {
                if constexpr (OUT_BF16)
                    reinterpret_cast<bf16*>(C)[(size_t)(r0 + j) * N + c] = (bf16)acc[m][n][j];
                else
                    reinterpret_cast<float*>(C)[(size_t)(r0 + j) * N + c] = acc[m][n][j];
            }
        }
    }
}

// ---------------------------------------------------------------- flash attention v6
// Swapped QK^T: sc[n] = mfma(kf, qf) -> S^T: D[row = t = n*16+lhi*4+j][col = q = l15].
// Each lane owns ONE q-row (l15): softmax = in-lane tree (16 vals) + 2 shfl_xor
// (lanes l15, l15+16, +32, +48 partition the 64 t's). P packed as 4x ds_write_b64.
// corr / 1/l for the PV output rows (q = lhi*4+j) via __shfl(cr, lhi*4+j, 16).
// exp2-domain (Q pre-scaled by 1/sqrt(DH)*log2e); defer-max THR=8.
#define QBLK 128
#define KVBLK 64
#define NQT (S/QBLK)

template<bool MASK>
__device__ __forceinline__ void attn_tile(
    int t0, int q0w, int l15, int lhi,
    const bf16x8* qf, const char* Kl, const char* Vl, char* Plw,
    f32x4* o, float& m_i, float& l_i)
{
    // QK^T (swapped operands; kf is the A-frag = K rows, qf the B-frag = Q cols)
    f32x4 sc[4] = {};
    __builtin_amdgcn_s_setprio(1);
    #pragma unroll
    for (int n = 0; n < 4; ++n) {
        int row = n * 16 + l15;
        #pragma unroll
        for (int kk = 0; kk < 4; ++kk) {
            bf16x8 kf = *reinterpret_cast<const bf16x8*>(
                Kl + row * 256 + ((((kk * 4 + lhi)) ^ (l15 & 7)) << 4));
            sc[n] = __builtin_amdgcn_mfma_f32_16x16x32_bf16(kf, qf[kk], sc[n], 0, 0, 0);
        }
    }
    __builtin_amdgcn_s_setprio(0);

    // per-lane softmax for q-row (q0w + l15); lane holds t = t0 + n*16 + lhi*4 + j
    const int qr = q0w + l15;
    float vals[16];
    #pragma unroll
    for (int n = 0; n < 4; ++n)
        #pragma unroll
        for (int j = 0; j < 4; ++j) {
            float v = sc[n][j];
            if constexpr (MASK) {
                int t = t0 + n * 16 + lhi * 4 + j;
                if (t > qr) v = -1e30f;
            }
            vals[n * 4 + j] = v;
        }

    float m8[8], m4[4];
    #pragma unroll
    for (int k = 0; k < 8; ++k) m8[k] = fmaxf(vals[k], vals[k + 8]);
    #pragma unroll
    for (int k = 0; k < 4; ++k) m4[k] = fmaxf(m8[k], m8[k + 4]);
    float mx = fmaxf(fmaxf(m4[0], m4[1]), fmaxf(m4[2], m4[3]));
    mx = fmaxf(mx, __shfl_xor(mx, 16));
    mx = fmaxf(mx, __shfl_xor(mx, 32));

    // defer-max: keep m unless it grew by > 8 (also absorbs fully-masked tiles)
    const float mnew = (mx <= m_i + 8.0f) ? m_i : mx;
    const float cr = exp2f(m_i - mnew);     // == 1.0 exactly when kept

    float p[16];
    #pragma unroll
    for (int k = 0; k < 16; ++k) p[k] = exp2f(vals[k] - mnew);
    float s8[8], s4[4];
    #pragma unroll
    for (int k = 0; k < 8; ++k) s8[k] = p[k] + p[k + 8];
    #pragma unroll
    for (int k = 0; k < 4; ++k) s4[k] = s8[k] + s8[k + 4];
    float rsum = (s4[0] + s4[1]) + (s4[2] + s4[3]);
    rsum += __shfl_xor(rsum, 16);
    rsum += __shfl_xor(rsum, 32);
    l_i = l_i * cr + rsum;
    m_i = mnew;

    // P -> LDS: row q = l15, 4 consecutive t per n -> packed b64 writes
    #pragma unroll
    for (int n = 0; n < 4; ++n) {
        bf16x4 w = { (bf16)p[n*4+0], (bf16)p[n*4+1], (bf16)p[n*4+2], (bf16)p[n*4+3] };
        int off = (l15 << 7) + (((n << 5) + (lhi << 3)) ^ ((l15 & 7) << 4));
        *reinterpret_cast<bf16x4*>(Plw + off) = w;
    }

    // rescale running O (rows q = lhi*4+j -> fetch corr from owner lane)
    float corr[4];
    #pragma unroll
    for (int j = 0; j < 4; ++j) corr[j] = __shfl(cr, lhi * 4 + j, 16);
    if ((corr[0] != 1.f) | (corr[1] != 1.f) | (corr[2] != 1.f) | (corr[3] != 1.f)) {
        #pragma unroll
        for (int n = 0; n < 8; ++n)
            #pragma unroll
            for (int j = 0; j < 4; ++j)
                o[n][j] *= corr[j];
    }

    // PV (A = P row q=l15, unchanged layout)
    __builtin_amdgcn_s_setprio(1);
    #pragma unroll
    for (int kk = 0; kk < 2; ++kk) {
        bf16x8 pf = *reinterpret_cast<const bf16x8*>(
            Plw + (l15 << 7) + ((((kk * 4 + lhi)) ^ (l15 & 7)) << 4));
        #pragma unroll
        for (int n = 0; n < 8; ++n) {
            int d = n * 16 + l15;
            bf16x8 vf = *reinterpret_cast<const bf16x8*>(
                Vl + (d << 7) + ((((kk * 4 + lhi)) ^ (d & 7)) << 4));
            o[n] = __builtin_amdgcn_mfma_f32_16x16x32_bf16(pf, vf, o[n], 0, 0, 0);
        }
    }
    __builtin_amdgcn_s_setprio(0);
}

__global__ __launch_bounds__(512) void flash_fwd6(
    const bf16* __restrict__ Q, const bf16* __restrict__ Kr,
    const bf16* __restrict__ VtG, bf16* __restrict__ ctx)
{
    extern __shared__ char fsm[];   // buf b: K @ b*32768, V @ +16384; P @ 65536 (8x2KB)

    const int tid  = threadIdx.x;
    const int lane = tid & 63;
    const int wave = tid >> 6;
    const int l15 = lane & 15;
    const int lhi = lane >> 4;
    const int bid = blockIdx.x;
    const int qt = (NQT - 1) - (bid >> 5);
    const int h  = ((bid & 7) << 2) | ((bid >> 3) & 3);
    const int g  = h >> 2;
    const int q0 = qt * QBLK;
    const int q0w = q0 + wave * 16;
    char* Plw = fsm + 65536 + wave * 2048;

    bf16x8 qf[4];
    {
        const bf16* qp = Q + (size_t)(q0w + l15) * HD + h * DH + lhi * 8;
        #pragma unroll
        for (int kk = 0; kk < 4; ++kk)
            qf[kk] = *reinterpret_cast<const bf16x8*>(qp + kk * 32);
    }

    f32x4 o[8] = {};
    float m_i = -1e30f;
    float l_i = 0.f;

    auto stage = [&](int t0, int buf) {
        char* Kl = fsm + buf * 32768;
        char* Vl = Kl + 16384;
        #pragma unroll
        for (int t = 0; t < 2; ++t) {
            int ch = t * 512 + tid;
            {
                int row = ch >> 4, ci = ch & 15;
                gload16(Kr + (size_t)(t0 + row) * GD + g * DH + ((ci ^ (row & 7)) << 3),
                        Kl + ch * 16);
            }
            {
                int d = ch >> 3, ci = ch & 7;
                gload16(VtG + (size_t)(g * DH + d) * S + t0 + ((ci ^ (d & 7)) << 3),
                        Vl + ch * 16);
            }
        }
    };

    const int nt = 2 * qt + 2;
    stage(0, 0);
    VMCNT(0);
    BARRIER();

    for (int it = 0; it < nt; ++it) {
        if (it + 1 < nt) stage((it + 1) * KVBLK, (it + 1) & 1);
        const char* Kl = fsm + (it & 1) * 32768;
        const char* Vl = Kl + 16384;
        if (it >= nt - 2)
            attn_tile<true>(it * KVBLK, q0w, l15, lhi, qf, Kl, Vl, Plw, o, m_i, l_i);
        else
            attn_tile<false>(it * KVBLK, q0w, l15, lhi, qf, Kl, Vl, Plw, o, m_i, l_i);
        VMCNT(0);
        BARRIER();
    }

    float lf[4];
    #pragma unroll
    for (int j = 0; j < 4; ++j) lf[j] = __shfl(l_i, lhi * 4 + j, 16);

    #pragma unroll
    for (int n = 0; n < 8; ++n) {
        int c = h * DH + n * 16 + l15;
        #pragma unroll
        for (int j = 0; j < 4; ++j) {
            int r = q0w + lhi * 4 + j;
            ctx[(size_t)r * HD + c] = (bf16)(o[n][j] / lf[j]);
        }
    }
}

// ---------------------------------------------------------------- launch
extern "C" void kernel_launch(void* const* d_in, const int* in_sizes, int n_in,
                              void* d_out, int out_size, void* d_ws, size_t ws_size,
                              hipStream_t stream)
{
    const float* x    = (const float*)d_in[0];
    const float* cosT = (const float*)d_in[2];
    const float* sinT = (const float*)d_in[3];
    const float* Wq   = (const float*)d_in[4];
    const float* Wk   = (const float*)d_in[5];
    const float* Wv   = (const float*)d_in[6];
    const float* Wo   = (const float*)d_in[7];
    float* out = (float*)d_out;

    const size_t MB = (size_t)1 << 20;
    char* ws = (char*)d_ws;
    bf16* xb  = (bf16*)ws;                         // 16MB
    bf16* ctx = (bf16*)(ws + 16 * MB);             // 16MB
    bf16* Qb  = (bf16*)d_out;                      // d_out scratch (dead until final GEMM)
    bf16* Kb  = Qb + (size_t)S * HD;
    bf16* Vb  = Kb + (size_t)S * GD;
    bf16* VtG = Vb + (size_t)S * GD;

    const bool fast = ws_size >= 112 * MB;
    const float qscale = 0.08838834764831845f * 1.4426950408889634f;

    hipFuncSetAttribute(reinterpret_cast<const void*>(&flash_fwd6),
                        hipFuncAttributeMaxDynamicSharedMemorySize, 81920);

    if (fast) {
        bf16* Wqkvt = (bf16*)(ws + 32 * MB);       // [6144][4096] bf16 = 48MB
        bf16* Wot   = (bf16*)(ws + 80 * MB);       // [4096][4096] bf16 = 32MB

        hipFuncSetAttribute(reinterpret_cast<const void*>(&gemm8p),
                            hipFuncAttributeMaxDynamicSharedMemorySize, 131072);
        hipFuncSetAttribute(reinterpret_cast<const void*>(&gemm3b),
                            hipFuncAttributeMaxDynamicSharedMemorySize, 147456);

        prep_fused<<<2048, 256, 0, stream>>>(x, xb, Wq, Wk, Wv, Wqkvt);

        gemm8p<<<256, 512, 131072, stream>>>(
            xb, Wqkvt, Qb, Kb, Vb, Wo, Wot, HD + 2 * GD, D, 192);

        rope_vt_fused<<<20608, 256, 0, stream>>>(Qb, Kb, Vb, VtG, cosT, sinT, qscale);

        flash_fwd6<<<NQT * H, 512, 81920, stream>>>(Qb, Kb, VtG, ctx);

        gemm3b<<<256, 512, 147456, stream>>>(ctx, Wot, out, D, HD);
    } else {
        cast_f32_bf16<<<(S * D / 4 + 255) / 256, 256, 0, stream>>>(x, xb, S * D / 4);

        gemm_aBf16<true><<<dim3(HD / BN, S / BM, 1), 256, 0, stream>>>(
            xb, Wq, Wq, (void*)Qb, (void*)Qb, S, HD, D);
        gemm_aBf16<true><<<dim3(GD / BN, S / BM, 2), 256, 0, stream>>>(
            xb, Wk, Wv, (void*)Kb, (void*)Vb, S, GD, D);

        rope_inplace<<<(S * HD / 2 + 255) / 256, 256, 0, stream>>>(Qb, cosT, sinT, HD, S * HD / 2, qscale);
        rope_inplace<<<(S * GD / 2 + 255) / 256, 256, 0, stream>>>(Kb, cosT, sinT, GD, S * GD / 2, 1.0f);

        transpose_to_bf16<false><<<dim3(GD / 256, S / 64), 256, 0, stream>>>(Vb, VtG, S, GD);

        flash_fwd6<<<NQT * H, 512, 81920, stream>>>(Qb, Kb, VtG, ctx);

        gemm_aBf16<false><<<dim3(D / BN, S / BM, 1), 256, 0, stream>>>(
            ctx, Wo, Wo, (void*)out, (void*)out, S, D, HD);
    }

    (void)in_sizes; (void)n_in; (void)out_size; (void)ws_size;
}